// Round 5
// baseline (756.956 us; speedup 1.0000x reference)
//
#include <hip/hip_runtime.h>
#include <hip/hip_cooperative_groups.h>
#include <hip/hip_bf16.h>
#include <math.h>

typedef __hip_bfloat16 bf16;
typedef __bf16 bf16x8 __attribute__((ext_vector_type(8)));
typedef float f32x4 __attribute__((ext_vector_type(4)));

#define NTOK 768      // B*L
#define SEQ  384
#define DDIM 256
#define VOC  32000

__device__ __forceinline__ float bf2f(bf16 v) { return __bfloat162float(v); }

// dtype probe: energy_levels = linspace(0,1,256).
// f32 storage: ushort[1] = top half of 0.0f = 0. bf16 storage: ushort[1] = bf16(1/255) != 0.
__device__ __forceinline__ bool probe_bf(const void* energy) {
    return ((const unsigned short*)energy)[1] != 0;
}
__device__ __forceinline__ float ldin(const void* p, long i, bool bf) {
    return bf ? bf2f(((const bf16*)p)[i]) : ((const float*)p)[i];
}

// block-wide reductions over 256 threads (4 waves); leading sync protects red reuse.
__device__ __forceinline__ float blk_sum256s(float v, float* red) {
    #pragma unroll
    for (int o = 32; o > 0; o >>= 1) v += __shfl_down(v, o, 64);
    __syncthreads();
    if ((threadIdx.x & 63) == 0) red[threadIdx.x >> 6] = v;
    __syncthreads();
    return red[0] + red[1] + red[2] + red[3];
}
__device__ __forceinline__ float blk_max256s(float v, float* red) {
    #pragma unroll
    for (int o = 32; o > 0; o >>= 1) v = fmaxf(v, __shfl_down(v, o, 64));
    __syncthreads();
    if ((threadIdx.x & 63) == 0) red[threadIdx.x >> 6] = v;
    __syncthreads();
    return fmaxf(fmaxf(red[0], red[1]), fmaxf(red[2], red[3]));
}

// emit per-layer normphase outputs (C/S, f32 nr/ni, bf16 hi/lo GEMM operands)
__device__ __forceinline__ void np_emit(int t, int d, float nrv, float niv, bool dual,
                                        const float* __restrict__ wm,
                                        float* __restrict__ nrO, float* __restrict__ niO,
                                        float* __restrict__ Co, float* __restrict__ So,
                                        bf16* __restrict__ ASh, bf16* __restrict__ ASl,
                                        bf16* __restrict__ BSh, bf16* __restrict__ BSl)
{
    float ph = atan2f(niv + 1e-8f, nrv + 1e-8f);
    float Cv = cosf(ph), Sv = sinf(ph);
    long idx = (long)t * DDIM + d;
    nrO[idx] = nrv;
    if (dual) niO[idx] = niv;
    Co[idx] = Cv;
    So[idx] = Sv;
    float wv = wm[d];
    float aC = Cv * wv, aS = Sv * wv;
    long o0 = (long)t * 512 + d, o1 = o0 + 256;
    bf16 h;
    h = __float2bfloat16(aC); ASh[o0] = h; ASl[o0] = __float2bfloat16(aC - bf2f(h));
    h = __float2bfloat16(aS); ASh[o1] = h; ASl[o1] = __float2bfloat16(aS - bf2f(h));
    h = __float2bfloat16(Cv); BSh[o0] = h; BSl[o0] = __float2bfloat16(Cv - bf2f(h));
    h = __float2bfloat16(Sv); BSh[o1] = h; BSl[o1] = __float2bfloat16(Sv - bf2f(h));
}

__device__ __forceinline__ void gload_lds16(const bf16* g, bf16* l) {
    __builtin_amdgcn_global_load_lds(
        (const __attribute__((address_space(1))) unsigned int*)g,
        (__attribute__((address_space(3))) unsigned int*)l,
        16, 0, 0);
}

// ---------------- per-layer unit functions (shared by coop + fallback) ----------------

// scores tile 32(l)x32(m): 4 waves, wave (wr,wc) owns 16x16. K=512.
__device__ __forceinline__ void scores_unit(int l0, int m0, int b, char* smem,
    const bf16* __restrict__ ASh, const bf16* __restrict__ ASl,
    const bf16* __restrict__ BSh, const bf16* __restrict__ BSl,
    float* __restrict__ scores)
{
    bf16* ldsA0 = (bf16*)smem;          // [32][64]
    bf16* ldsA1 = ldsA0 + 2048;
    bf16* ldsB0 = ldsA1 + 2048;
    bf16* ldsB1 = ldsB0 + 2048;
    int tid = threadIdx.x, lane = tid & 63, wid = tid >> 6;
    int wr = wid >> 1, wc = wid & 1;
    int lrow = lane >> 3, cbs = (lane & 7) ^ lrow;
    const bf16* src = (wid == 0 ? ASh : wid == 1 ? ASl : wid == 2 ? BSh : BSl)
                      + (size_t)(b * SEQ + (wid < 2 ? l0 : m0)) * 512;
    bf16* ld = (wid == 0 ? ldsA0 : wid == 1 ? ldsA1 : wid == 2 ? ldsB0 : ldsB1);
    f32x4 acc = {};
    for (int k0 = 0; k0 < 512; k0 += 64) {
        #pragma unroll
        for (int q = 0; q < 4; ++q)
            gload_lds16(src + (size_t)(q * 8 + lrow) * 512 + k0 + cbs * 8, ld + q * 512);
        __syncthreads();
        #pragma unroll
        for (int ks = 0; ks < 2; ++ks) {
            int cb = ks * 64 + (lane >> 4) * 16;
            int rowb = wc * 16 + (lane & 15);
            int offb = rowb * 128 + (cb ^ ((rowb & 7) << 4));
            bf16x8 bh = *(const bf16x8*)((const char*)ldsB0 + offb);
            bf16x8 bl = *(const bf16x8*)((const char*)ldsB1 + offb);
            int rowa = wr * 16 + (lane & 15);
            int offa = rowa * 128 + (cb ^ ((rowa & 7) << 4));
            bf16x8 ah = *(const bf16x8*)((const char*)ldsA0 + offa);
            bf16x8 al = *(const bf16x8*)((const char*)ldsA1 + offa);
            acc = __builtin_amdgcn_mfma_f32_16x16x32_bf16(ah, bh, acc, 0, 0, 0);
            acc = __builtin_amdgcn_mfma_f32_16x16x32_bf16(ah, bl, acc, 0, 0, 0);
            acc = __builtin_amdgcn_mfma_f32_16x16x32_bf16(al, bh, acc, 0, 0, 0);
        }
        __syncthreads();
    }
    int mm = m0 + wc * 16 + (lane & 15);
    int lbase = l0 + wr * 16 + (lane >> 4) * 4;
    #pragma unroll
    for (int i = 0; i < 4; ++i)
        scores[(size_t)(b * SEQ + lbase + i) * SEQ + mm] = acc[i];
}

// transpose 64x64 tile of nr/ni -> K-major bf16 hi/lo
__device__ __forceinline__ void transpose_unit(int m0, int d0, int b, char* smem, int dual,
    const float* __restrict__ nr, const float* __restrict__ ni,
    bf16* __restrict__ nrTh, bf16* __restrict__ nrTl,
    bf16* __restrict__ niTh, bf16* __restrict__ niTl)
{
    float* tr = (float*)smem;           // [64][65]
    float* ti = tr + 64 * 65;
    int c = threadIdx.x & 63, rr = threadIdx.x >> 6;
    #pragma unroll
    for (int i = 0; i < 16; ++i) {
        int r = i * 4 + rr;
        tr[r * 65 + c] = nr[(b * SEQ + m0 + r) * DDIM + d0 + c];
        if (dual) ti[r * 65 + c] = ni[(b * SEQ + m0 + r) * DDIM + d0 + c];
    }
    __syncthreads();
    #pragma unroll
    for (int i = 0; i < 16; ++i) {
        int dd = i * 4 + rr;
        long o = (long)(b * DDIM + d0 + dd) * SEQ + m0 + c;
        float vr = tr[c * 65 + dd];
        bf16 h;
        h = __float2bfloat16(vr); nrTh[o] = h; nrTl[o] = __float2bfloat16(vr - bf2f(h));
        if (dual) {
            float vi = ti[c * 65 + dd];
            h = __float2bfloat16(vi); niTh[o] = h; niTl[o] = __float2bfloat16(vi - bf2f(h));
        }
    }
    __syncthreads();    // protect smem reuse by next unit
}

// partial column sums of C,S (16 rows per unit)
__device__ __forceinline__ void sums_unit(int c, int b,
    const float* __restrict__ C, const float* __restrict__ S,
    float* __restrict__ Cp, float* __restrict__ Sp)
{
    int d = threadIdx.x;
    float cs = 0.f, ss = 0.f;
    int base = (b * SEQ + c * 16) * DDIM + d;
    #pragma unroll
    for (int m = 0; m < 16; ++m) { cs += C[base + m * DDIM]; ss += S[base + m * DDIM]; }
    Cp[(b * 24 + c) * DDIM + d] = cs;
    Sp[(b * 24 + c) * DDIM + d] = ss;
}

// softmax over one row (256 threads cover 384 columns), emits P hi/lo
__device__ __forceinline__ void softmax_unit(int row, float* red,
    const float* __restrict__ scores, const int* __restrict__ x,
    bf16* __restrict__ Ph, bf16* __restrict__ Pl)
{
    int b = row / SEQ;
    int tid = threadIdx.x;
    float s1 = scores[(size_t)row * SEQ + tid];
    if (x[b * SEQ + tid] == 0) s1 = -__builtin_inff();
    float s2 = -__builtin_inff();
    if (tid < 128) {
        s2 = scores[(size_t)row * SEQ + 256 + tid];
        if (x[b * SEQ + 256 + tid] == 0) s2 = -__builtin_inff();
    }
    float mx = blk_max256s(fmaxf(s1, s2), red);
    float e1 = expf(s1 - mx);
    float e2 = (tid < 128) ? expf(s2 - mx) : 0.f;
    float sum = blk_sum256s(e1 + e2, red);
    float p1 = fminf(fmaxf(e1 / sum, 1e-6f), 1.0f);
    bf16 h = __float2bfloat16(p1);
    Ph[(size_t)row * SEQ + tid] = h;
    Pl[(size_t)row * SEQ + tid] = __float2bfloat16(p1 - bf2f(h));
    if (tid < 128) {
        float p2 = fminf(fmaxf(e2 / sum, 1e-6f), 1.0f);
        h = __float2bfloat16(p2);
        Ph[(size_t)row * SEQ + 256 + tid] = h;
        Pl[(size_t)row * SEQ + 256 + tid] = __float2bfloat16(p2 - bf2f(h));
    }
}

// outgemm tile 32(l)x32(d): out_r (and out_i when dual) = P @ nrT/niT. K=384.
__device__ __forceinline__ void outgemm_unit(int l0, int d0, int b, char* smem, int dual,
    const bf16* __restrict__ Ph, const bf16* __restrict__ Pl,
    const bf16* __restrict__ nrTh, const bf16* __restrict__ nrTl,
    const bf16* __restrict__ niTh, const bf16* __restrict__ niTl,
    float* __restrict__ outr, float* __restrict__ outi)
{
    bf16* ldsA0 = (bf16*)smem;          // [32][64] each
    bf16* ldsA1 = ldsA0 + 2048;
    bf16* ldsB0 = ldsA1 + 2048;
    bf16* ldsB1 = ldsB0 + 2048;
    bf16* ldsB2 = ldsB1 + 2048;
    bf16* ldsB3 = ldsB2 + 2048;
    int tid = threadIdx.x, lane = tid & 63, wid = tid >> 6;
    int wr = wid >> 1, wc = wid & 1;
    int lrow = lane >> 3, cbs = (lane & 7) ^ lrow;

    const bf16* sA  = (wid == 0 ? Ph : Pl) + (size_t)(b * SEQ + l0) * SEQ;
    const bf16* sB1 = (wid == 2 ? nrTh : nrTl) + (size_t)(b * DDIM + d0) * SEQ;
    const bf16* sB2 = (wid == 2 ? niTh : niTl) + (size_t)(b * DDIM + d0) * SEQ;

    f32x4 accr = {}, acci = {};

    for (int k0 = 0; k0 < SEQ; k0 += 64) {
        if (wid < 2) {
            bf16* ld = (wid == 0) ? ldsA0 : ldsA1;
            #pragma unroll
            for (int q = 0; q < 4; ++q)
                gload_lds16(sA + (size_t)(q * 8 + lrow) * SEQ + k0 + cbs * 8, ld + q * 512);
        } else {
            bf16* l1 = (wid == 2) ? ldsB0 : ldsB1;
            #pragma unroll
            for (int q = 0; q < 4; ++q)
                gload_lds16(sB1 + (size_t)(q * 8 + lrow) * SEQ + k0 + cbs * 8, l1 + q * 512);
            if (dual) {
                bf16* l2 = (wid == 2) ? ldsB2 : ldsB3;
                #pragma unroll
                for (int q = 0; q < 4; ++q)
                    gload_lds16(sB2 + (size_t)(q * 8 + lrow) * SEQ + k0 + cbs * 8, l2 + q * 512);
            }
        }
        __syncthreads();
        #pragma unroll
        for (int ks = 0; ks < 2; ++ks) {
            int cb = ks * 64 + (lane >> 4) * 16;
            int rowb = wc * 16 + (lane & 15);
            int offb = rowb * 128 + (cb ^ ((rowb & 7) << 4));
            int rowa = wr * 16 + (lane & 15);
            int offa = rowa * 128 + (cb ^ ((rowa & 7) << 4));
            bf16x8 ah = *(const bf16x8*)((const char*)ldsA0 + offa);
            bf16x8 al = *(const bf16x8*)((const char*)ldsA1 + offa);
            bf16x8 brh = *(const bf16x8*)((const char*)ldsB0 + offb);
            bf16x8 brl = *(const bf16x8*)((const char*)ldsB1 + offb);
            accr = __builtin_amdgcn_mfma_f32_16x16x32_bf16(ah, brh, accr, 0, 0, 0);
            accr = __builtin_amdgcn_mfma_f32_16x16x32_bf16(ah, brl, accr, 0, 0, 0);
            accr = __builtin_amdgcn_mfma_f32_16x16x32_bf16(al, brh, accr, 0, 0, 0);
            if (dual) {
                bf16x8 bih = *(const bf16x8*)((const char*)ldsB2 + offb);
                bf16x8 bil = *(const bf16x8*)((const char*)ldsB3 + offb);
                acci = __builtin_amdgcn_mfma_f32_16x16x32_bf16(ah, bih, acci, 0, 0, 0);
                acci = __builtin_amdgcn_mfma_f32_16x16x32_bf16(ah, bil, acci, 0, 0, 0);
                acci = __builtin_amdgcn_mfma_f32_16x16x32_bf16(al, bih, acci, 0, 0, 0);
            }
        }
        __syncthreads();
    }

    int d = d0 + wc * 16 + (lane & 15);
    int lb = l0 + wr * 16 + (lane >> 4) * 4;
    #pragma unroll
    for (int i = 0; i < 4; ++i) {
        size_t idx = (size_t)(b * SEQ + lb + i) * DDIM + d;
        outr[idx] = accr[i];
        if (dual) outi[idx] = acci[i];
    }
}

// coherence + phase preservation + residual LN update (+ fused next-layer emit)
__device__ __forceinline__ void update_unit(int t, float* red,
    float* __restrict__ realA,
    const float* __restrict__ outr, const float* __restrict__ outi,
    const float* __restrict__ C, const float* __restrict__ S,
    const float* __restrict__ Cp, const float* __restrict__ Sp,
    const void* __restrict__ pp, const void* __restrict__ cfac,
    const void* __restrict__ energy, int layer, int mode,
    const float* __restrict__ wmNext,
    float* __restrict__ nrO, float* __restrict__ Co, float* __restrict__ So,
    bf16* __restrict__ ASh, bf16* __restrict__ ASl,
    bf16* __restrict__ BSh, bf16* __restrict__ BSl,
    bf16* __restrict__ Ah, bf16* __restrict__ Al)
{
    bool bf = probe_bf(energy);
    int d = threadIdx.x;
    int b = t / SEQ;
    long idx = (long)t * DDIM + d;
    float cs = 0.f, ss = 0.f;
    #pragma unroll
    for (int c = 0; c < 24; ++c) {
        cs += Cp[(b * 24 + c) * DDIM + d];
        ss += Sp[(b * 24 + c) * DDIM + d];
    }
    float dotv = C[idx] * cs + S[idx] * ss;
    float coh = blk_sum256s(dotv, red) * (1.0f / (384.f * 256.f));
    float cf = (1.f / (1.f + expf(-ldin(cfac, layer, bf)))) * coh;
    float orr = outr[idx], oii = outi[idx];
    float phase = atan2f(oii + 1e-8f, orr + 1e-8f);
    float pres = (1.f / (1.f + expf(-ldin(pp, layer * DDIM + d, bf)))) * cf;
    float pr = orr * cosf(phase * pres);
    float v = realA[idx] + 0.01f * pr;
    float mu = blk_sum256s(v, red) * (1.f / 256.f);
    float dv = v - mu;
    float var = blk_sum256s(dv * dv, red) * (1.f / 256.f);
    float nv = dv / sqrtf(var + 1e-8f);
    nv = fminf(fmaxf(nv, -1.f), 1.f);
    realA[idx] = nv;
    float mu2 = blk_sum256s(nv, red) * (1.f / 256.f);
    float dv2 = nv - mu2;
    float var2 = blk_sum256s(dv2 * dv2, red) * (1.f / 256.f);
    float nn = dv2 / sqrtf(var2 + 1e-5f);
    if (mode == 0) {
        np_emit(t, d, nn, nn, false, wmNext, nrO, nullptr, Co, So, ASh, ASl, BSh, BSl);
    } else {
        bf16 h = __float2bfloat16(nn);
        Ah[idx] = h;
        Al[idx] = __float2bfloat16(nn - bf2f(h));
    }
}

// ---------------- cooperative mega-kernel for the 3-layer loop ----------------
struct CoopArgs {
    const int* x;
    const void* pp; const void* cfac; const void* energy;
    float* realA; float* nr; float* ni; float* Cc; float* Ss;
    float* outr; float* outi; float* attn; float* Cp; float* Sp;
    const float* wmAll;
    bf16 *ASh, *ASl, *BSh, *BSl, *Phb, *Plb;
    bf16 *nrTh, *nrTl, *niTh, *niTl, *Ah, *Al;
};

__global__ __launch_bounds__(256)
void coop_layers(CoopArgs a)
{
    __shared__ __align__(16) char smem[33280];
    cooperative_groups::grid_group g = cooperative_groups::this_grid();
    int bid = blockIdx.x, G = gridDim.x;
    for (int layer = 0; layer < 3; ++layer) {
        int dual = (layer == 0);
        // Phase A: scores (288) | transpose (48) | sums (48)
        for (int u = bid; u < 384; u += G) {
            if (u < 288)
                scores_unit((u % 12) * 32, ((u / 12) % 12) * 32, u / 144, smem,
                            a.ASh, a.ASl, a.BSh, a.BSl, a.attn);
            else if (u < 336) {
                int v = u - 288;
                transpose_unit((v % 6) * 64, ((v / 6) % 4) * 64, v / 24, smem, dual,
                               a.nr, a.ni, a.nrTh, a.nrTl, a.niTh, a.niTl);
            } else {
                int w = u - 336;
                sums_unit(w % 24, w / 24, a.Cc, a.Ss, a.Cp, a.Sp);
            }
        }
        g.sync();
        // Phase B: softmax
        for (int row = bid; row < NTOK; row += G)
            softmax_unit(row, (float*)smem, a.attn, a.x, a.Phb, a.Plb);
        g.sync();
        // Phase C: outgemm (192 units)
        for (int u = bid; u < 192; u += G)
            outgemm_unit((u % 12) * 32, ((u / 12) % 8) * 32, u / 96, smem, dual,
                         a.Phb, a.Plb, a.nrTh, a.nrTl, a.niTh, a.niTl, a.outr, a.outi);
        g.sync();
        // Phase D: update (+ next-layer emit / final prep)
        int mode = (layer < 2) ? 0 : 1;
        const float* wmN = a.wmAll + ((layer + 1 < 3) ? (layer + 1) * DDIM : 0);
        for (int t = bid; t < NTOK; t += G)
            update_unit(t, (float*)smem, a.realA, a.outr, dual ? a.outi : a.outr,
                        a.Cc, a.Ss, a.Cp, a.Sp, a.pp, a.cfac, a.energy, layer, mode, wmN,
                        a.nr, a.Cc, a.Ss, a.ASh, a.ASl, a.BSh, a.BSl, a.Ah, a.Al);
        g.sync();
    }
}

// ---------------- fallback wrappers (used if cooperative launch unavailable) ----------------
__global__ __launch_bounds__(256)
void scores_k(const bf16* ASh, const bf16* ASl, const bf16* BSh, const bf16* BSl, float* scores)
{
    __shared__ __align__(16) char smem[16384];
    scores_unit(blockIdx.x * 32, blockIdx.y * 32, blockIdx.z, smem, ASh, ASl, BSh, BSl, scores);
}
__global__ __launch_bounds__(256)
void transpose_k(const float* nr, const float* ni, bf16* nrTh, bf16* nrTl,
                 bf16* niTh, bf16* niTl, int dual)
{
    __shared__ __align__(16) char smem[33280];
    transpose_unit(blockIdx.x * 64, blockIdx.y * 64, blockIdx.z, smem, dual,
                   nr, ni, nrTh, nrTl, niTh, niTl);
}
__global__ __launch_bounds__(256)
void sums_k(const float* C, const float* S, float* Cp, float* Sp)
{ sums_unit(blockIdx.x, blockIdx.y, C, S, Cp, Sp); }
__global__ __launch_bounds__(256)
void softmax_k(const float* scores, const int* x, bf16* Ph, bf16* Pl)
{
    __shared__ float red[4];
    softmax_unit(blockIdx.x, red, scores, x, Ph, Pl);
}
__global__ __launch_bounds__(256)
void outgemm_k(const bf16* Ph, const bf16* Pl, const bf16* nrTh, const bf16* nrTl,
               const bf16* niTh, const bf16* niTl, float* outr, float* outi, int dual)
{
    __shared__ __align__(16) char smem[24576];
    outgemm_unit(blockIdx.x * 32, blockIdx.y * 32, blockIdx.z, smem, dual,
                 Ph, Pl, nrTh, nrTl, niTh, niTl, outr, outi);
}
__global__ __launch_bounds__(256)
void update_k(float* realA, const float* outr, const float* outi,
              const float* C, const float* S, const float* Cp, const float* Sp,
              const void* pp, const void* cfac, const void* energy, int layer, int mode,
              const float* wmNext, float* nrO, float* Co, float* So,
              bf16* ASh, bf16* ASl, bf16* BSh, bf16* BSl, bf16* Ah, bf16* Al)
{
    __shared__ float red[4];
    update_unit(blockIdx.x, red, realA, outr, outi, C, S, Cp, Sp, pp, cfac, energy,
                layer, mode, wmNext, nrO, Co, So, ASh, ASl, BSh, BSl, Ah, Al);
}

// ---------------- Stage 1: embedding + phase space + normphase(layer 0) fused ----------------
__global__ __launch_bounds__(256)
void phase_kernel(const int* __restrict__ x, const void* __restrict__ emb,
                  const void* __restrict__ lph, const void* __restrict__ iw,
                  const void* __restrict__ energy, const void* __restrict__ excf,
                  const float* __restrict__ wm0,
                  float* __restrict__ realO,
                  float* __restrict__ nrO, float* __restrict__ niO,
                  float* __restrict__ Co, float* __restrict__ So,
                  bf16* __restrict__ ASh, bf16* __restrict__ ASl,
                  bf16* __restrict__ BSh, bf16* __restrict__ BSl)
{
    __shared__ float red[4];
    bool bf = probe_bf(energy);
    int t = blockIdx.x, d = threadIdx.x;
    int tok = x[t];
    float re = ldin(emb, (long)tok * DDIM + d, bf) * 0.1f;
    float fr = 0.f, fi = 0.f;
    const float ca[3] = {1.0f, -0.5f, -0.5f};
    const float sa[3] = {0.0f, 0.86602540378443864676f, -0.86602540378443864676f};
    #pragma unroll
    for (int i = 0; i < 3; ++i) {
        float pa = tanhf(ldin(lph, i * DDIM + d, bf)) * 3.14159265358979323846f;
        pa = pa * 1.61803398874989484820f;
        float vr = re * cosf(pa);
        float vi = re * sinf(pa);
        float mu = blk_sum256s(vr, red) * (1.f / 256.f);
        float dv = vr - mu;
        float var = blk_sum256s(dv * dv, red) * (1.f / 256.f);
        float r = dv / sqrtf(var + 1e-8f);
        mu = blk_sum256s(vi, red) * (1.f / 256.f);
        float di = vi - mu;
        var = blk_sum256s(di * di, red) * (1.f / 256.f);
        float im = di / sqrtf(var + 1e-8f);
        float w = tanhf(ldin(iw, i * DDIM + d, bf));
        r *= w; im *= w;
        fr = fr + r * ca[i] - im * sa[i];
        fi = fi + r * sa[i] + im * ca[i];
    }
    float amp = sqrtf(fr * fr + fi * fi + 1e-8f);
    float ex = expf(ldin(energy, d, bf)) * ldin(excf, 0, bf);
    if (amp < 0.1f) { fr += ex; fi += ex; }
    float nrm = sqrtf(fr * fr + fi * fi + 1e-8f);
    float rr = fminf(fmaxf(fr / nrm, -1.f), 1.f);
    float ii = fminf(fmaxf(fi / nrm, -1.f), 1.f);
    realO[t * DDIM + d] = rr;
    // fused normphase (layer 0, dual)
    float mu = blk_sum256s(rr, red) * (1.f / 256.f);
    float dv = rr - mu;
    float var = blk_sum256s(dv * dv, red) * (1.f / 256.f);
    float nrv = dv / sqrtf(var + 1e-5f);
    mu = blk_sum256s(ii, red) * (1.f / 256.f);
    float di = ii - mu;
    var = blk_sum256s(di * di, red) * (1.f / 256.f);
    float niv = di / sqrtf(var + 1e-5f);
    np_emit(t, d, nrv, niv, true, wm0, nrO, niO, Co, So, ASh, ASl, BSh, BSl);
}

// w_mean rows for all 3 layers, scale folded
__global__ __launch_bounds__(256)
void wmean_kernel(const void* __restrict__ W, const void* __restrict__ energy,
                  float* __restrict__ wmAll)
{
    bool bf = probe_bf(energy);
    int row = blockIdx.x * 4 + (threadIdx.x >> 6);
    int lane = threadIdx.x & 63;
    long base = (long)row * DDIM + lane * 4;
    float s = 0.f;
    #pragma unroll
    for (int j = 0; j < 4; ++j) s += ldin(W, base + j, bf);
    #pragma unroll
    for (int o = 32; o > 0; o >>= 1) s += __shfl_down(s, o, 64);
    if (lane == 0) wmAll[row] = s * (1.f / 256.f) * 0.0625f;
}

// ---------------- Final stage: bf16x3 MFMA vocab GEMM ----------------
__global__ __launch_bounds__(256)
void fold_kernel(const void* __restrict__ W, const void* __restrict__ energy,
                 bf16* __restrict__ Bh, bf16* __restrict__ Bl)
{
    __shared__ float tile[64][65];
    bool bf = probe_bf(energy);
    int v0 = blockIdx.x * 64, d0 = blockIdx.y * 64;
    int c = threadIdx.x & 63, rr = threadIdx.x >> 6;
    #pragma unroll
    for (int i = 0; i < 16; ++i) {
        int r = i * 4 + rr;
        long i1 = (long)(d0 + r) * VOC + v0 + c;
        long i2 = (long)(d0 + r + 256) * VOC + v0 + c;
        tile[r][c] = ldin(W, i1, bf) + ldin(W, i2, bf);
    }
    __syncthreads();
    int d = threadIdx.x & 63, vv = threadIdx.x >> 6;
    #pragma unroll
    for (int i = 0; i < 16; ++i) {
        int v = i * 4 + vv;
        float s = tile[d][v];
        bf16 h = __float2bfloat16(s);
        long o = (long)(v0 + v) * DDIM + d0 + d;
        Bh[o] = h;
        Bl[o] = __float2bfloat16(s - __bfloat162float(h));
    }
}

__global__ __launch_bounds__(512, 4)
void vocab_gemm(const bf16* __restrict__ Ah, const bf16* __restrict__ Al,
                const bf16* __restrict__ Bh, const bf16* __restrict__ Bl,
                const void* __restrict__ bias, const void* __restrict__ energy,
                void* __restrict__ out)
{
    __shared__ bf16 lds[4][128 * 64];
    bool bf = probe_bf(energy);
    int flat = blockIdx.x + blockIdx.y * 6;        // 0..1499
    int xcd = flat & 7, bidx = flat >> 3;
    int swz = (xcd < 4) ? xcd * 188 + bidx : 752 + (xcd - 4) * 187 + bidx;
    int m0 = (swz % 6) * 128, n0 = (swz / 6) * 128;
    int tid = threadIdx.x, lane = tid & 63, wid = tid >> 6;
    int wm = wid >> 2, wn = wid & 3;
    int arr = wid >> 1, half = wid & 1;

    const bf16* src;
    if      (arr == 0) src = Ah + (size_t)m0 * DDIM;
    else if (arr == 1) src = Al + (size_t)m0 * DDIM;
    else if (arr == 2) src = Bh + (size_t)n0 * DDIM;
    else               src = Bl + (size_t)n0 * DDIM;
    src += (size_t)half * 64 * DDIM;
    bf16* ldst = &lds[arr][half * 64 * 64];
    int lrow = lane >> 3;
    int cbs  = (lane & 7) ^ lrow;

    f32x4 acc[4][2] = {};

    for (int k0 = 0; k0 < DDIM; k0 += 64) {
        #pragma unroll
        for (int q = 0; q < 8; ++q) {
            const bf16* gp = src + (size_t)(q * 8 + lrow) * DDIM + k0 + cbs * 8;
            gload_lds16(gp, ldst + q * 512);
        }
        __syncthreads();
        #pragma unroll
        for (int ks = 0; ks < 2; ++ks) {
            int cb = ks * 64 + (lane >> 4) * 16;
            bf16x8 bhf[2], blf[2];
            #pragma unroll
            for (int fn = 0; fn < 2; ++fn) {
                int row = wn * 32 + fn * 16 + (lane & 15);
                int off = row * 128 + (cb ^ ((row & 7) << 4));
                bhf[fn] = *(const bf16x8*)((const char*)&lds[2][0] + off);
                blf[fn] = *(const bf16x8*)((const char*)&lds[3][0] + off);
            }
            #pragma unroll
            for (int fm = 0; fm < 4; ++fm) {
                int row = wm * 64 + fm * 16 + (lane & 15);
                int off = row * 128 + (cb ^ ((row & 7) << 4));
                bf16x8 ah = *(const bf16x8*)((const char*)&lds[0][0] + off);
                bf16x8 al = *(const bf16x8*)((const char*)&lds[1][0] + off);
                #pragma unroll
                for (int fn = 0; fn < 2; ++fn) {
                    acc[fm][fn] = __builtin_amdgcn_mfma_f32_16x16x32_bf16(ah, bhf[fn], acc[fm][fn], 0, 0, 0);
                    acc[fm][fn] = __builtin_amdgcn_mfma_f32_16x16x32_bf16(ah, blf[fn], acc[fm][fn], 0, 0, 0);
                    acc[fm][fn] = __builtin_amdgcn_mfma_f32_16x16x32_bf16(al, bhf[fn], acc[fm][fn], 0, 0, 0);
                }
            }
        }
        __syncthreads();
    }

    #pragma unroll
    for (int fn = 0; fn < 2; ++fn) {
        int n = n0 + wn * 32 + fn * 16 + (lane & 15);
        float bv = ldin(bias, n, bf);
        #pragma unroll
        for (int fm = 0; fm < 4; ++fm) {
            int mbase = m0 + wm * 64 + fm * 16 + (lane >> 4) * 4;
            #pragma unroll
            for (int i = 0; i < 4; ++i) {
                float lg = (acc[fm][fn][i] + bv) * 0.1f;
                lg = fminf(fmaxf(lg, -10.f), 10.f);
                size_t idx = (size_t)(mbase + i) * VOC + n;
                if (bf) ((bf16*)out)[idx] = __float2bfloat16(lg);
                else    ((float*)out)[idx] = lg;
            }
        }
    }
}

extern "C" void kernel_launch(void* const* d_in, const int* in_sizes, int n_in,
                              void* d_out, int out_size, void* d_ws, size_t ws_size,
                              hipStream_t stream) {
    (void)in_sizes; (void)n_in; (void)out_size; (void)ws_size;
    const int*  x        = (const int*)d_in[0];
    const void* emb_real = d_in[1];
    const void* lph      = d_in[3];
    const void* iw       = d_in[4];
    const void* energy   = d_in[5];
    const void* excf     = d_in[6];
    const void* pp       = d_in[7];
    const void* cfac     = d_in[8];
    const void* Wattn    = d_in[9];
    const void* out_w    = d_in[10];
    const void* out_b    = d_in[11];

    float* ws = (float*)d_ws;
    const int TD = NTOK * DDIM;   // 196608
    float* realA = ws;
    float* nr    = realA + TD;
    float* ni    = nr + TD;
    float* Cc    = ni + TD;
    float* Ss    = Cc + TD;
    float* outr  = Ss + TD;
    float* outi  = outr + TD;
    float* attn  = outi + TD;
    float* Cp    = attn + 2 * SEQ * SEQ;
    float* Sp    = Cp + 48 * DDIM;
    float* wmAll = Sp + 48 * DDIM;
    bf16* Ah  = (bf16*)(wmAll + 768);
    bf16* Al  = Ah + (size_t)NTOK * DDIM;
    bf16* Wth = Al + (size_t)NTOK * DDIM;
    bf16* Wtl = Wth + (size_t)VOC * DDIM;
    bf16* ASh = Wtl + (size_t)VOC * DDIM;
    bf16* ASl = ASh + (size_t)NTOK * 512;
    bf16* BSh = ASl + (size_t)NTOK * 512;
    bf16* BSl = BSh + (size_t)NTOK * 512;
    bf16* Phb = BSl + (size_t)NTOK * 512;
    bf16* Plb = Phb + (size_t)NTOK * SEQ;
    bf16* nrTh = Plb + (size_t)NTOK * SEQ;
    bf16* nrTl = nrTh + (size_t)NTOK * DDIM;
    bf16* niTh = nrTl + (size_t)NTOK * DDIM;
    bf16* niTl = niTh + (size_t)NTOK * DDIM;

    fold_kernel<<<dim3(VOC / 64, DDIM / 64), 256, 0, stream>>>(out_w, energy, Wth, Wtl);
    wmean_kernel<<<192, 256, 0, stream>>>(Wattn, energy, wmAll);
    phase_kernel<<<NTOK, 256, 0, stream>>>(x, emb_real, lph, iw, energy, excf, wmAll,
                                           realA, nr, ni, Cc, Ss, ASh, ASl, BSh, BSl);

    // cooperative grid size (cached): co-residency guaranteed via occupancy query
    static int coop_grid = -2;
    if (coop_grid == -2) {
        int dev = 0, nb = 0, ncu = 0;
        hipGetDevice(&dev);
        hipDeviceProp_t prop;
        if (hipGetDeviceProperties(&prop, dev) == hipSuccess) ncu = prop.multiProcessorCount;
        if (ncu <= 0) ncu = 256;
        if (hipOccupancyMaxActiveBlocksPerMultiprocessor(&nb, (const void*)coop_layers, 256, 0)
                != hipSuccess || nb < 1)
            coop_grid = -1;
        else {
            long gsz = (long)nb * ncu;
            coop_grid = (int)(gsz < 768 ? gsz : 768);
        }
    }

    bool did_coop = false;
    if (coop_grid > 0) {
        CoopArgs ca;
        ca.x = x; ca.pp = pp; ca.cfac = cfac; ca.energy = energy;
        ca.realA = realA; ca.nr = nr; ca.ni = ni; ca.Cc = Cc; ca.Ss = Ss;
        ca.outr = outr; ca.outi = outi; ca.attn = attn; ca.Cp = Cp; ca.Sp = Sp;
        ca.wmAll = wmAll;
        ca.ASh = ASh; ca.ASl = ASl; ca.BSh = BSh; ca.BSl = BSl;
        ca.Phb = Phb; ca.Plb = Plb;
        ca.nrTh = nrTh; ca.nrTl = nrTl; ca.niTh = niTh; ca.niTl = niTl;
        ca.Ah = Ah; ca.Al = Al;
        void* params[] = { &ca };
        if (hipLaunchCooperativeKernel((const void*)coop_layers, dim3(coop_grid), dim3(256),
                                       params, 0, stream) == hipSuccess)
            did_coop = true;
    }
    if (!did_coop) {
        for (int layer = 0; layer < 3; ++layer) {
            int dual = (layer == 0);
            sums_k<<<dim3(24, 2), 256, 0, stream>>>(Cc, Ss, Cp, Sp);
            transpose_k<<<dim3(6, 4, 2), 256, 0, stream>>>(nr, ni, nrTh, nrTl, niTh, niTl, dual);
            scores_k<<<dim3(12, 12, 2), 256, 0, stream>>>(ASh, ASl, BSh, BSl, attn);
            softmax_k<<<NTOK, 256, 0, stream>>>(attn, x, Phb, Plb);
            outgemm_k<<<dim3(12, 8, 2), 256, 0, stream>>>(Phb, Plb, nrTh, nrTl, niTh, niTl,
                                                          outr, outi, dual);
            update_k<<<NTOK, 256, 0, stream>>>(realA, outr, dual ? outi : outr, Cc, Ss,
                                               Cp, Sp, pp, cfac, energy, layer,
                                               (layer < 2) ? 0 : 1,
                                               wmAll + (layer + 1 < 3 ? (layer + 1) * DDIM : 0),
                                               nr, Cc, Ss, ASh, ASl, BSh, BSl, Ah, Al);
        }
    }
    vocab_gemm<<<dim3(6, VOC / 128), 512, 0, stream>>>(Ah, Al, Wth, Wtl, out_b, energy, (void*)d_out);
}

// Round 6
// 363.728 us; speedup vs baseline: 2.0811x; 2.0811x over previous
//
#include <hip/hip_runtime.h>
#include <hip/hip_bf16.h>
#include <math.h>

typedef __hip_bfloat16 bf16;
typedef __bf16 bf16x8 __attribute__((ext_vector_type(8)));
typedef float f32x4 __attribute__((ext_vector_type(4)));

#define NTOK 768      // B*L
#define SEQ  384
#define DDIM 256
#define VOC  32000

__device__ __forceinline__ float bf2f(bf16 v) { return __bfloat162float(v); }

// dtype probe: energy_levels = linspace(0,1,256).
// f32 storage: ushort[1] = top half of 0.0f = 0. bf16 storage: ushort[1] = bf16(1/255) != 0.
__device__ __forceinline__ bool probe_bf(const void* energy) {
    return ((const unsigned short*)energy)[1] != 0;
}
__device__ __forceinline__ float ldin(const void* p, long i, bool bf) {
    return bf ? bf2f(((const bf16*)p)[i]) : ((const float*)p)[i];
}

// block-wide reductions over 256 threads (4 waves); leading sync protects red reuse.
__device__ __forceinline__ float blk_sum256s(float v, float* red) {
    #pragma unroll
    for (int o = 32; o > 0; o >>= 1) v += __shfl_down(v, o, 64);
    __syncthreads();
    if ((threadIdx.x & 63) == 0) red[threadIdx.x >> 6] = v;
    __syncthreads();
    return red[0] + red[1] + red[2] + red[3];
}

// emit per-layer normphase outputs (C/S, f32 nr/ni, bf16 hi/lo GEMM operands)
__device__ __forceinline__ void np_emit(int t, int d, float nrv, float niv, bool dual,
                                        const float* __restrict__ wm,
                                        float* __restrict__ nrO, float* __restrict__ niO,
                                        float* __restrict__ Co, float* __restrict__ So,
                                        bf16* __restrict__ ASh, bf16* __restrict__ ASl,
                                        bf16* __restrict__ BSh, bf16* __restrict__ BSl)
{
    float ph = atan2f(niv + 1e-8f, nrv + 1e-8f);
    float Cv = cosf(ph), Sv = sinf(ph);
    long idx = (long)t * DDIM + d;
    nrO[idx] = nrv;
    if (dual) niO[idx] = niv;
    Co[idx] = Cv;
    So[idx] = Sv;
    float wv = wm[d];
    float aC = Cv * wv, aS = Sv * wv;
    long o0 = (long)t * 512 + d, o1 = o0 + 256;
    bf16 h;
    h = __float2bfloat16(aC); ASh[o0] = h; ASl[o0] = __float2bfloat16(aC - bf2f(h));
    h = __float2bfloat16(aS); ASh[o1] = h; ASl[o1] = __float2bfloat16(aS - bf2f(h));
    h = __float2bfloat16(Cv); BSh[o0] = h; BSl[o0] = __float2bfloat16(Cv - bf2f(h));
    h = __float2bfloat16(Sv); BSh[o1] = h; BSl[o1] = __float2bfloat16(Sv - bf2f(h));
}

__device__ __forceinline__ void gload_lds16(const bf16* g, bf16* l) {
    __builtin_amdgcn_global_load_lds(
        (const __attribute__((address_space(1))) unsigned int*)g,
        (__attribute__((address_space(3))) unsigned int*)l,
        16, 0, 0);
}

// ---------------- per-layer unit functions ----------------

// scores tile 32(l)x32(m): 4 waves, wave (wr,wc) owns 16x16. K=512.
__device__ __forceinline__ void scores_unit(int l0, int m0, int b, char* smem,
    const bf16* __restrict__ ASh, const bf16* __restrict__ ASl,
    const bf16* __restrict__ BSh, const bf16* __restrict__ BSl,
    float* __restrict__ scores)
{
    bf16* ldsA0 = (bf16*)smem;          // [32][64]
    bf16* ldsA1 = ldsA0 + 2048;
    bf16* ldsB0 = ldsA1 + 2048;
    bf16* ldsB1 = ldsB0 + 2048;
    int tid = threadIdx.x, lane = tid & 63, wid = tid >> 6;
    int wr = wid >> 1, wc = wid & 1;
    int lrow = lane >> 3, cbs = (lane & 7) ^ lrow;
    const bf16* src = (wid == 0 ? ASh : wid == 1 ? ASl : wid == 2 ? BSh : BSl)
                      + (size_t)(b * SEQ + (wid < 2 ? l0 : m0)) * 512;
    bf16* ld = (wid == 0 ? ldsA0 : wid == 1 ? ldsA1 : wid == 2 ? ldsB0 : ldsB1);
    f32x4 acc = {};
    for (int k0 = 0; k0 < 512; k0 += 64) {
        #pragma unroll
        for (int q = 0; q < 4; ++q)
            gload_lds16(src + (size_t)(q * 8 + lrow) * 512 + k0 + cbs * 8, ld + q * 512);
        __syncthreads();
        #pragma unroll
        for (int ks = 0; ks < 2; ++ks) {
            int cb = ks * 64 + (lane >> 4) * 16;
            int rowb = wc * 16 + (lane & 15);
            int offb = rowb * 128 + (cb ^ ((rowb & 7) << 4));
            bf16x8 bh = *(const bf16x8*)((const char*)ldsB0 + offb);
            bf16x8 bl = *(const bf16x8*)((const char*)ldsB1 + offb);
            int rowa = wr * 16 + (lane & 15);
            int offa = rowa * 128 + (cb ^ ((rowa & 7) << 4));
            bf16x8 ah = *(const bf16x8*)((const char*)ldsA0 + offa);
            bf16x8 al = *(const bf16x8*)((const char*)ldsA1 + offa);
            acc = __builtin_amdgcn_mfma_f32_16x16x32_bf16(ah, bh, acc, 0, 0, 0);
            acc = __builtin_amdgcn_mfma_f32_16x16x32_bf16(ah, bl, acc, 0, 0, 0);
            acc = __builtin_amdgcn_mfma_f32_16x16x32_bf16(al, bh, acc, 0, 0, 0);
        }
        __syncthreads();
    }
    int mm = m0 + wc * 16 + (lane & 15);
    int lbase = l0 + wr * 16 + (lane >> 4) * 4;
    #pragma unroll
    for (int i = 0; i < 4; ++i)
        scores[(size_t)(b * SEQ + lbase + i) * SEQ + mm] = acc[i];
}

// transpose 64x64 tile of nr/ni -> K-major bf16 hi/lo
__device__ __forceinline__ void transpose_unit(int m0, int d0, int b, char* smem, int dual,
    const float* __restrict__ nr, const float* __restrict__ ni,
    bf16* __restrict__ nrTh, bf16* __restrict__ nrTl,
    bf16* __restrict__ niTh, bf16* __restrict__ niTl)
{
    float* tr = (float*)smem;           // [64][65]
    float* ti = tr + 64 * 65;
    int c = threadIdx.x & 63, rr = threadIdx.x >> 6;
    #pragma unroll
    for (int i = 0; i < 16; ++i) {
        int r = i * 4 + rr;
        tr[r * 65 + c] = nr[(b * SEQ + m0 + r) * DDIM + d0 + c];
        if (dual) ti[r * 65 + c] = ni[(b * SEQ + m0 + r) * DDIM + d0 + c];
    }
    __syncthreads();
    #pragma unroll
    for (int i = 0; i < 16; ++i) {
        int dd = i * 4 + rr;
        long o = (long)(b * DDIM + d0 + dd) * SEQ + m0 + c;
        float vr = tr[c * 65 + dd];
        bf16 h;
        h = __float2bfloat16(vr); nrTh[o] = h; nrTl[o] = __float2bfloat16(vr - bf2f(h));
        if (dual) {
            float vi = ti[c * 65 + dd];
            h = __float2bfloat16(vi); niTh[o] = h; niTl[o] = __float2bfloat16(vi - bf2f(h));
        }
    }
}

// partial column sums of C,S (16 rows per unit)
__device__ __forceinline__ void sums_unit(int c, int b,
    const float* __restrict__ C, const float* __restrict__ S,
    float* __restrict__ Cp, float* __restrict__ Sp)
{
    int d = threadIdx.x;
    float cs = 0.f, ss = 0.f;
    int base = (b * SEQ + c * 16) * DDIM + d;
    #pragma unroll
    for (int m = 0; m < 16; ++m) { cs += C[base + m * DDIM]; ss += S[base + m * DDIM]; }
    Cp[(b * 24 + c) * DDIM + d] = cs;
    Sp[(b * 24 + c) * DDIM + d] = ss;
}

// ---------------- Phase A: scores (288) | transpose (48) | sums (48) in one launch ----------------
__global__ __launch_bounds__(256)
void phaseA_k(const bf16* __restrict__ ASh, const bf16* __restrict__ ASl,
              const bf16* __restrict__ BSh, const bf16* __restrict__ BSl,
              float* __restrict__ attn,
              const float* __restrict__ nr, const float* __restrict__ ni,
              bf16* __restrict__ nrTh, bf16* __restrict__ nrTl,
              bf16* __restrict__ niTh, bf16* __restrict__ niTl,
              const float* __restrict__ Cc, const float* __restrict__ Ss,
              float* __restrict__ Cp, float* __restrict__ Sp, int dual)
{
    __shared__ __align__(16) char smem[33280];
    int u = blockIdx.x;
    if (u < 288) {
        scores_unit((u % 12) * 32, ((u / 12) % 12) * 32, u / 144, smem,
                    ASh, ASl, BSh, BSl, attn);
    } else if (u < 336) {
        int v = u - 288;
        transpose_unit((v % 6) * 64, ((v / 6) % 4) * 64, v / 24, smem, dual,
                       nr, ni, nrTh, nrTl, niTh, niTl);
    } else {
        int w = u - 336;
        sums_unit(w % 24, w / 24, Cc, Ss, Cp, Sp);
    }
}

// ---------------- Fused softmax + PV GEMM ----------------
// Block: 32 l-rows x 32 d-cols. Softmax of the 32 rows computed in-block from f32
// scores (wave-parallel), P hi/lo stored XOR-swizzled in LDS, then bf16x3 MFMA
// against nrT (pass 0) and niT (pass 1, dual only). K=384.
__global__ __launch_bounds__(256)
void outfused_k(const float* __restrict__ scores, const int* __restrict__ x,
                const bf16* __restrict__ nrTh, const bf16* __restrict__ nrTl,
                const bf16* __restrict__ niTh, const bf16* __restrict__ niTl,
                float* __restrict__ outr, float* __restrict__ outi, int dual)
{
    __shared__ __align__(16) char PhL[32 * 768];   // P hi, row stride 768B (384 bf16)
    __shared__ __align__(16) char PlL[32 * 768];   // P lo
    __shared__ __align__(16) char Bb[8192];        // B tile hi(4KB) + lo(4KB)
    int l0 = blockIdx.x * 32, d0 = blockIdx.y * 32, b = blockIdx.z;
    int tid = threadIdx.x, lane = tid & 63, wid = tid >> 6;

    // mask bits for this lane's 6 columns (col = lane + j*64)
    int msk = 0;
    #pragma unroll
    for (int j = 0; j < 6; ++j)
        if (x[b * SEQ + lane + j * 64] == 0) msk |= (1 << j);

    // softmax: wave w handles rows w*8 .. w*8+7
    #pragma unroll
    for (int r8 = 0; r8 < 8; ++r8) {
        int r = wid * 8 + r8;
        const float* srow = scores + (size_t)(b * SEQ + l0 + r) * SEQ;
        float v[6];
        float mx = -__builtin_inff();
        #pragma unroll
        for (int j = 0; j < 6; ++j) {
            float s = srow[lane + j * 64];
            if (msk & (1 << j)) s = -__builtin_inff();
            v[j] = s;
            mx = fmaxf(mx, s);
        }
        #pragma unroll
        for (int o = 32; o > 0; o >>= 1) mx = fmaxf(mx, __shfl_xor(mx, o, 64));
        float e[6], sum = 0.f;
        #pragma unroll
        for (int j = 0; j < 6; ++j) { e[j] = expf(v[j] - mx); sum += e[j]; }
        #pragma unroll
        for (int o = 32; o > 0; o >>= 1) sum += __shfl_xor(sum, o, 64);
        #pragma unroll
        for (int j = 0; j < 6; ++j) {
            float p = fminf(fmaxf(e[j] / sum, 1e-6f), 1.0f);
            bf16 h = __float2bfloat16(p);
            bf16 l = __float2bfloat16(p - bf2f(h));
            int c2 = (lane + j * 64) * 2;
            int swz = ((c2 & ~15) ^ ((r & 7) << 4)) | (c2 & 15);
            *(bf16*)(PhL + r * 768 + swz) = h;
            *(bf16*)(PlL + r * 768 + swz) = l;
        }
    }
    __syncthreads();

    int wr = wid >> 1, wc = wid & 1;
    int lrow = lane >> 3, cbs = (lane & 7) ^ lrow;
    int half = wid >> 1;                 // B-staging row-half for this wave
    int npass = dual ? 2 : 1;

    for (int pass = 0; pass < npass; ++pass) {
        const bf16* srcB = ((wid & 1) ? (pass ? niTl : nrTl) : (pass ? niTh : nrTh))
                           + (size_t)(b * DDIM + d0) * SEQ;
        bf16* ldB = (bf16*)(Bb + (wid & 1) * 4096 + half * 2048);
        f32x4 acc = {};
        for (int k0 = 0; k0 < SEQ; k0 += 64) {
            #pragma unroll
            for (int q = 0; q < 2; ++q)
                gload_lds16(srcB + (size_t)(half * 16 + q * 8 + lrow) * SEQ + k0 + cbs * 8,
                            ldB + q * 512);
            __syncthreads();
            #pragma unroll
            for (int ks = 0; ks < 2; ++ks) {
                int cbk = ks * 64 + (lane >> 4) * 16;         // bytes within 128B k-tile
                int rowb = wc * 16 + (lane & 15);
                int offb = rowb * 128 + (cbk ^ ((rowb & 7) << 4));
                bf16x8 bh = *(const bf16x8*)(Bb + offb);
                bf16x8 bl = *(const bf16x8*)(Bb + 4096 + offb);
                int rowa = wr * 16 + (lane & 15);
                int cba = k0 * 2 + cbk;                        // absolute bytes in 768B row
                int offa = rowa * 768 + (cba ^ ((rowa & 7) << 4));
                bf16x8 ah = *(const bf16x8*)(PhL + offa);
                bf16x8 al = *(const bf16x8*)(PlL + offa);
                acc = __builtin_amdgcn_mfma_f32_16x16x32_bf16(ah, bh, acc, 0, 0, 0);
                acc = __builtin_amdgcn_mfma_f32_16x16x32_bf16(ah, bl, acc, 0, 0, 0);
                acc = __builtin_amdgcn_mfma_f32_16x16x32_bf16(al, bh, acc, 0, 0, 0);
            }
            __syncthreads();
        }
        float* dst = pass ? outi : outr;
        int d = d0 + wc * 16 + (lane & 15);
        int lb = l0 + wr * 16 + (lane >> 4) * 4;
        #pragma unroll
        for (int i = 0; i < 4; ++i)
            dst[(size_t)(b * SEQ + lb + i) * DDIM + d] = acc[i];
    }
}

// coherence + phase preservation + residual LN update (+ fused next-layer emit)
__global__ __launch_bounds__(256)
void update_k(float* __restrict__ realA,
              const float* __restrict__ outr, const float* __restrict__ outi,
              const float* __restrict__ C, const float* __restrict__ S,
              const float* __restrict__ Cp, const float* __restrict__ Sp,
              const void* __restrict__ pp, const void* __restrict__ cfac,
              const void* __restrict__ energy, int layer, int mode,
              const float* __restrict__ wmNext,
              float* __restrict__ nrO, float* __restrict__ Co, float* __restrict__ So,
              bf16* __restrict__ ASh, bf16* __restrict__ ASl,
              bf16* __restrict__ BSh, bf16* __restrict__ BSl,
              bf16* __restrict__ Ah, bf16* __restrict__ Al)
{
    __shared__ float red[4];
    bool bf = probe_bf(energy);
    int t = blockIdx.x, d = threadIdx.x;
    int b = t / SEQ;
    long idx = (long)t * DDIM + d;
    float cs = 0.f, ss = 0.f;
    #pragma unroll
    for (int c = 0; c < 24; ++c) {
        cs += Cp[(b * 24 + c) * DDIM + d];
        ss += Sp[(b * 24 + c) * DDIM + d];
    }
    float dotv = C[idx] * cs + S[idx] * ss;
    float coh = blk_sum256s(dotv, red) * (1.0f / (384.f * 256.f));
    float cf = (1.f / (1.f + expf(-ldin(cfac, layer, bf)))) * coh;
    float orr = outr[idx], oii = outi[idx];
    float phase = atan2f(oii + 1e-8f, orr + 1e-8f);
    float pres = (1.f / (1.f + expf(-ldin(pp, layer * DDIM + d, bf)))) * cf;
    float pr = orr * cosf(phase * pres);
    float v = realA[idx] + 0.01f * pr;
    float mu = blk_sum256s(v, red) * (1.f / 256.f);
    float dv = v - mu;
    float var = blk_sum256s(dv * dv, red) * (1.f / 256.f);
    float nv = dv / sqrtf(var + 1e-8f);
    nv = fminf(fmaxf(nv, -1.f), 1.f);
    realA[idx] = nv;
    float mu2 = blk_sum256s(nv, red) * (1.f / 256.f);
    float dv2 = nv - mu2;
    float var2 = blk_sum256s(dv2 * dv2, red) * (1.f / 256.f);
    float nn = dv2 / sqrtf(var2 + 1e-5f);
    if (mode == 0) {
        np_emit(t, d, nn, nn, false, wmNext, nrO, nullptr, Co, So, ASh, ASl, BSh, BSl);
    } else {
        bf16 h = __float2bfloat16(nn);
        Ah[idx] = h;
        Al[idx] = __float2bfloat16(nn - bf2f(h));
    }
}

// ---------------- Stage 1: embedding + phase space + normphase(layer 0) fused ----------------
__global__ __launch_bounds__(256)
void phase_kernel(const int* __restrict__ x, const void* __restrict__ emb,
                  const void* __restrict__ lph, const void* __restrict__ iw,
                  const void* __restrict__ energy, const void* __restrict__ excf,
                  const float* __restrict__ wm0,
                  float* __restrict__ realO,
                  float* __restrict__ nrO, float* __restrict__ niO,
                  float* __restrict__ Co, float* __restrict__ So,
                  bf16* __restrict__ ASh, bf16* __restrict__ ASl,
                  bf16* __restrict__ BSh, bf16* __restrict__ BSl)
{
    __shared__ float red[4];
    bool bf = probe_bf(energy);
    int t = blockIdx.x, d = threadIdx.x;
    int tok = x[t];
    float re = ldin(emb, (long)tok * DDIM + d, bf) * 0.1f;
    float fr = 0.f, fi = 0.f;
    const float ca[3] = {1.0f, -0.5f, -0.5f};
    const float sa[3] = {0.0f, 0.86602540378443864676f, -0.86602540378443864676f};
    #pragma unroll
    for (int i = 0; i < 3; ++i) {
        float pa = tanhf(ldin(lph, i * DDIM + d, bf)) * 3.14159265358979323846f;
        pa = pa * 1.61803398874989484820f;
        float vr = re * cosf(pa);
        float vi = re * sinf(pa);
        float mu = blk_sum256s(vr, red) * (1.f / 256.f);
        float dv = vr - mu;
        float var = blk_sum256s(dv * dv, red) * (1.f / 256.f);
        float r = dv / sqrtf(var + 1e-8f);
        mu = blk_sum256s(vi, red) * (1.f / 256.f);
        float di = vi - mu;
        var = blk_sum256s(di * di, red) * (1.f / 256.f);
        float im = di / sqrtf(var + 1e-8f);
        float w = tanhf(ldin(iw, i * DDIM + d, bf));
        r *= w; im *= w;
        fr = fr + r * ca[i] - im * sa[i];
        fi = fi + r * sa[i] + im * ca[i];
    }
    float amp = sqrtf(fr * fr + fi * fi + 1e-8f);
    float ex = expf(ldin(energy, d, bf)) * ldin(excf, 0, bf);
    if (amp < 0.1f) { fr += ex; fi += ex; }
    float nrm = sqrtf(fr * fr + fi * fi + 1e-8f);
    float rr = fminf(fmaxf(fr / nrm, -1.f), 1.f);
    float ii = fminf(fmaxf(fi / nrm, -1.f), 1.f);
    realO[t * DDIM + d] = rr;
    float mu = blk_sum256s(rr, red) * (1.f / 256.f);
    float dv = rr - mu;
    float var = blk_sum256s(dv * dv, red) * (1.f / 256.f);
    float nrv = dv / sqrtf(var + 1e-5f);
    mu = blk_sum256s(ii, red) * (1.f / 256.f);
    float di = ii - mu;
    var = blk_sum256s(di * di, red) * (1.f / 256.f);
    float niv = di / sqrtf(var + 1e-5f);
    np_emit(t, d, nrv, niv, true, wm0, nrO, niO, Co, So, ASh, ASl, BSh, BSl);
}

// ---------------- prep1: fold out_w (2000 blocks) | wmean (192 blocks) ----------------
__global__ __launch_bounds__(256)
void prep1_k(const void* __restrict__ W, const void* __restrict__ Wattn,
             const void* __restrict__ energy,
             bf16* __restrict__ Bh, bf16* __restrict__ Bl, float* __restrict__ wmAll)
{
    bool bf = probe_bf(energy);
    int u = blockIdx.x;
    if (u < 2000) {
        __shared__ float tile[64][65];
        int v0 = (u % 500) * 64, d0 = (u / 500) * 64;
        int c = threadIdx.x & 63, rr = threadIdx.x >> 6;
        #pragma unroll
        for (int i = 0; i < 16; ++i) {
            int r = i * 4 + rr;
            long i1 = (long)(d0 + r) * VOC + v0 + c;
            long i2 = (long)(d0 + r + 256) * VOC + v0 + c;
            tile[r][c] = ldin(W, i1, bf) + ldin(W, i2, bf);
        }
        __syncthreads();
        int d = threadIdx.x & 63, vv = threadIdx.x >> 6;
        #pragma unroll
        for (int i = 0; i < 16; ++i) {
            int v = i * 4 + vv;
            float s = tile[d][v];
            bf16 h = __float2bfloat16(s);
            long o = (long)(v0 + v) * DDIM + d0 + d;
            Bh[o] = h;
            Bl[o] = __float2bfloat16(s - __bfloat162float(h));
        }
    } else {
        int row = (u - 2000) * 4 + (threadIdx.x >> 6);
        int lane = threadIdx.x & 63;
        long base = (long)row * DDIM + lane * 4;
        float s = 0.f;
        #pragma unroll
        for (int j = 0; j < 4; ++j) s += ldin(Wattn, base + j, bf);
        #pragma unroll
        for (int o = 32; o > 0; o >>= 1) s += __shfl_down(s, o, 64);
        if (lane == 0) wmAll[row] = s * (1.f / 256.f) * 0.0625f;
    }
}

// ---------------- Final stage: bf16x3 MFMA vocab GEMM ----------------
__global__ __launch_bounds__(512, 4)
void vocab_gemm(const bf16* __restrict__ Ah, const bf16* __restrict__ Al,
                const bf16* __restrict__ Bh, const bf16* __restrict__ Bl,
                const void* __restrict__ bias, const void* __restrict__ energy,
                void* __restrict__ out)
{
    __shared__ bf16 lds[4][128 * 64];
    bool bf = probe_bf(energy);
    int flat = blockIdx.x + blockIdx.y * 6;        // 0..1499
    int xcd = flat & 7, bidx = flat >> 3;
    int swz = (xcd < 4) ? xcd * 188 + bidx : 752 + (xcd - 4) * 187 + bidx;
    int m0 = (swz % 6) * 128, n0 = (swz / 6) * 128;
    int tid = threadIdx.x, lane = tid & 63, wid = tid >> 6;
    int wm = wid >> 2, wn = wid & 3;
    int arr = wid >> 1, half = wid & 1;

    const bf16* src;
    if      (arr == 0) src = Ah + (size_t)m0 * DDIM;
    else if (arr == 1) src = Al + (size_t)m0 * DDIM;
    else if (arr == 2) src = Bh + (size_t)n0 * DDIM;
    else               src = Bl + (size_t)n0 * DDIM;
    src += (size_t)half * 64 * DDIM;
    bf16* ldst = &lds[arr][half * 64 * 64];
    int lrow = lane >> 3;
    int cbs  = (lane & 7) ^ lrow;

    f32x4 acc[4][2] = {};

    for (int k0 = 0; k0 < DDIM; k0 += 64) {
        #pragma unroll
        for (int q = 0; q < 8; ++q) {
            const bf16* gp = src + (size_t)(q * 8 + lrow) * DDIM + k0 + cbs * 8;
            gload_lds16(gp, ldst + q * 512);
        }
        __syncthreads();
        #pragma unroll
        for (int ks = 0; ks < 2; ++ks) {
            int cb = ks * 64 + (lane >> 4) * 16;
            bf16x8 bhf[2], blf[2];
            #pragma unroll
            for (int fn = 0; fn < 2; ++fn) {
                int row = wn * 32 + fn * 16 + (lane & 15);
                int off = row * 128 + (cb ^ ((row & 7) << 4));
                bhf[fn] = *(const bf16x8*)((const char*)&lds[2][0] + off);
                blf[fn] = *(const bf16x8*)((const char*)&lds[3][0] + off);
            }
            #pragma unroll
            for (int fm = 0; fm < 4; ++fm) {
                int row = wm * 64 + fm * 16 + (lane & 15);
                int off = row * 128 + (cb ^ ((row & 7) << 4));
                bf16x8 ah = *(const bf16x8*)((const char*)&lds[0][0] + off);
                bf16x8 al = *(const bf16x8*)((const char*)&lds[1][0] + off);
                #pragma unroll
                for (int fn = 0; fn < 2; ++fn) {
                    acc[fm][fn] = __builtin_amdgcn_mfma_f32_16x16x32_bf16(ah, bhf[fn], acc[fm][fn], 0, 0, 0);
                    acc[fm][fn] = __builtin_amdgcn_mfma_f32_16x16x32_bf16(ah, blf[fn], acc[fm][fn], 0, 0, 0);
                    acc[fm][fn] = __builtin_amdgcn_mfma_f32_16x16x32_bf16(al, bhf[fn], acc[fm][fn], 0, 0, 0);
                }
            }
        }
        __syncthreads();
    }

    #pragma unroll
    for (int fn = 0; fn < 2; ++fn) {
        int n = n0 + wn * 32 + fn * 16 + (lane & 15);
        float bv = ldin(bias, n, bf);
        #pragma unroll
        for (int fm = 0; fm < 4; ++fm) {
            int mbase = m0 + wm * 64 + fm * 16 + (lane >> 4) * 4;
            #pragma unroll
            for (int i = 0; i < 4; ++i) {
                float lg = (acc[fm][fn][i] + bv) * 0.1f;
                lg = fminf(fmaxf(lg, -10.f), 10.f);
                size_t idx = (size_t)(mbase + i) * VOC + n;
                if (bf) ((bf16*)out)[idx] = __float2bfloat16(lg);
                else    ((float*)out)[idx] = lg;
            }
        }
    }
}

extern "C" void kernel_launch(void* const* d_in, const int* in_sizes, int n_in,
                              void* d_out, int out_size, void* d_ws, size_t ws_size,
                              hipStream_t stream) {
    (void)in_sizes; (void)n_in; (void)out_size; (void)ws_size;
    const int*  x        = (const int*)d_in[0];
    const void* emb_real = d_in[1];
    const void* lph      = d_in[3];
    const void* iw       = d_in[4];
    const void* energy   = d_in[5];
    const void* excf     = d_in[6];
    const void* pp       = d_in[7];
    const void* cfac     = d_in[8];
    const void* Wattn    = d_in[9];
    const void* out_w    = d_in[10];
    const void* out_b    = d_in[11];

    float* ws = (float*)d_ws;
    const int TD = NTOK * DDIM;   // 196608
    float* realA = ws;
    float* nr    = realA + TD;
    float* ni    = nr + TD;
    float* Cc    = ni + TD;
    float* Ss    = Cc + TD;
    float* outr  = Ss + TD;
    float* outi  = outr + TD;
    float* attn  = outi + TD;
    float* Cp    = attn + 2 * SEQ * SEQ;
    float* Sp    = Cp + 48 * DDIM;
    float* wmAll = Sp + 48 * DDIM;
    bf16* Ah  = (bf16*)(wmAll + 768);
    bf16* Al  = Ah + (size_t)NTOK * DDIM;
    bf16* Wth = Al + (size_t)NTOK * DDIM;
    bf16* Wtl = Wth + (size_t)VOC * DDIM;
    bf16* ASh = Wtl + (size_t)VOC * DDIM;
    bf16* ASl = ASh + (size_t)NTOK * 512;
    bf16* BSh = ASl + (size_t)NTOK * 512;
    bf16* BSl = BSh + (size_t)NTOK * 512;
    bf16* nrTh = BSl + (size_t)NTOK * 512;     // [2][256][384]
    bf16* nrTl = nrTh + (size_t)NTOK * DDIM;
    bf16* niTh = nrTl + (size_t)NTOK * DDIM;
    bf16* niTl = niTh + (size_t)NTOK * DDIM;

    prep1_k<<<2192, 256, 0, stream>>>(out_w, Wattn, energy, Wth, Wtl, wmAll);
    phase_kernel<<<NTOK, 256, 0, stream>>>(x, emb_real, lph, iw, energy, excf, wmAll,
                                           realA, nr, ni, Cc, Ss, ASh, ASl, BSh, BSl);
    for (int layer = 0; layer < 3; ++layer) {
        int dual = (layer == 0);
        phaseA_k<<<384, 256, 0, stream>>>(ASh, ASl, BSh, BSl, attn, nr, ni,
                                          nrTh, nrTl, niTh, niTl, Cc, Ss, Cp, Sp, dual);
        outfused_k<<<dim3(12, 8, 2), 256, 0, stream>>>(attn, x, nrTh, nrTl, niTh, niTl,
                                                       outr, outi, dual);
        update_k<<<NTOK, 256, 0, stream>>>(realA, outr, dual ? outi : outr, Cc, Ss,
                                           Cp, Sp, pp, cfac, energy, layer,
                                           (layer < 2) ? 0 : 1,
                                           wmAll + (layer + 1 < 3 ? (layer + 1) * DDIM : 0),
                                           nr, Cc, Ss, ASh, ASl, BSh, BSl, Ah, Al);
    }
    vocab_gemm<<<dim3(6, VOC / 128), 512, 0, stream>>>(Ah, Al, Wth, Wtl, out_b, energy, (void*)d_out);
}

// Round 8
// 360.516 us; speedup vs baseline: 2.0996x; 1.0089x over previous
//
#include <hip/hip_runtime.h>
#include <hip/hip_bf16.h>
#include <math.h>

typedef __hip_bfloat16 bf16;
typedef __bf16 bf16x8 __attribute__((ext_vector_type(8)));
typedef float f32x4 __attribute__((ext_vector_type(4)));

#define NTOK 768      // B*L
#define SEQ  384
#define DDIM 256
#define VOC  32000

__device__ __forceinline__ float bf2f(bf16 v) { return __bfloat162float(v); }

// dtype probe: energy_levels = linspace(0,1,256).
// f32 storage: ushort[1] = top half of 0.0f = 0. bf16 storage: ushort[1] = bf16(1/255) != 0.
__device__ __forceinline__ bool probe_bf(const void* energy) {
    return ((const unsigned short*)energy)[1] != 0;
}
__device__ __forceinline__ float ldin(const void* p, long i, bool bf) {
    return bf ? bf2f(((const bf16*)p)[i]) : ((const float*)p)[i];
}

// block-wide reductions over 256 threads (4 waves); leading sync protects red reuse.
__device__ __forceinline__ float blk_sum256s(float v, float* red) {
    #pragma unroll
    for (int o = 32; o > 0; o >>= 1) v += __shfl_down(v, o, 64);
    __syncthreads();
    if ((threadIdx.x & 63) == 0) red[threadIdx.x >> 6] = v;
    __syncthreads();
    return red[0] + red[1] + red[2] + red[3];
}

// layer-0 (dual) normphase emit: K=512 operand rows
__device__ __forceinline__ void np_emit(int t, int d, float nrv, float niv,
                                        const float* __restrict__ wm,
                                        float* __restrict__ nrO, float* __restrict__ niO,
                                        float* __restrict__ Co, float* __restrict__ So,
                                        bf16* __restrict__ ASh, bf16* __restrict__ ASl,
                                        bf16* __restrict__ BSh, bf16* __restrict__ BSl)
{
    float ph = atan2f(niv + 1e-8f, nrv + 1e-8f);
    float Cv = cosf(ph), Sv = sinf(ph);
    long idx = (long)t * DDIM + d;
    nrO[idx] = nrv;
    niO[idx] = niv;
    Co[idx] = Cv;
    So[idx] = Sv;
    float wv = wm[d];
    float aC = Cv * wv, aS = Sv * wv;
    long o0 = (long)t * 512 + d, o1 = o0 + 256;
    bf16 h;
    h = __float2bfloat16(aC); ASh[o0] = h; ASl[o0] = __float2bfloat16(aC - bf2f(h));
    h = __float2bfloat16(aS); ASh[o1] = h; ASl[o1] = __float2bfloat16(aS - bf2f(h));
    h = __float2bfloat16(Cv); BSh[o0] = h; BSl[o0] = __float2bfloat16(Cv - bf2f(h));
    h = __float2bfloat16(Sv); BSh[o1] = h; BSl[o1] = __float2bfloat16(Sv - bf2f(h));
}

__device__ __forceinline__ void gload_lds16(const bf16* g, bf16* l) {
    __builtin_amdgcn_global_load_lds(
        (const __attribute__((address_space(1))) unsigned int*)g,
        (__attribute__((address_space(3))) unsigned int*)l,
        16, 0, 0);
}

// ---------------- per-layer unit functions ----------------

// scores tile 32(l)x32(m), K=kd (512 layer 0, 256 folded layers 1-2), LDS double-buffered.
// Buffer bi at smem + bi*16384; arrays A-hi/A-lo/B-hi/B-lo at +0/4096/8192/12288 bytes.
__device__ __forceinline__ void scores_unit(int l0, int m0, int b, char* smem, int kd,
    const bf16* __restrict__ ASh, const bf16* __restrict__ ASl,
    const bf16* __restrict__ BSh, const bf16* __restrict__ BSl,
    float* __restrict__ scores)
{
    int tid = threadIdx.x, lane = tid & 63, wid = tid >> 6;
    int wr = wid >> 1, wc = wid & 1;
    int lrow = lane >> 3, cbs = (lane & 7) ^ lrow;
    const bf16* src = (wid == 0 ? ASh : wid == 1 ? ASl : wid == 2 ? BSh : BSl)
                      + (size_t)(b * SEQ + (wid < 2 ? l0 : m0)) * kd;
    bf16* ld0 = (bf16*)(smem + wid * 4096);
    bf16* ld1 = (bf16*)(smem + 16384 + wid * 4096);
    f32x4 acc = {};
    #pragma unroll
    for (int q = 0; q < 4; ++q)
        gload_lds16(src + (size_t)(q * 8 + lrow) * kd + cbs * 8, ld0 + q * 512);
    __syncthreads();
    int cur = 0;
    for (int k0 = 0; k0 < kd; k0 += 64) {
        if (k0 + 64 < kd) {                       // prefetch next chunk into other buf
            bf16* ld = cur ? ld0 : ld1;
            #pragma unroll
            for (int q = 0; q < 4; ++q)
                gload_lds16(src + (size_t)(q * 8 + lrow) * kd + (k0 + 64) + cbs * 8, ld + q * 512);
        }
        const char* base = smem + cur * 16384;
        #pragma unroll
        for (int ks = 0; ks < 2; ++ks) {
            int cb = ks * 64 + (lane >> 4) * 16;
            int rowb = wc * 16 + (lane & 15);
            int offb = rowb * 128 + (cb ^ ((rowb & 7) << 4));
            bf16x8 bh = *(const bf16x8*)(base + 8192 + offb);
            bf16x8 bl = *(const bf16x8*)(base + 12288 + offb);
            int rowa = wr * 16 + (lane & 15);
            int offa = rowa * 128 + (cb ^ ((rowa & 7) << 4));
            bf16x8 ah = *(const bf16x8*)(base + offa);
            bf16x8 al = *(const bf16x8*)(base + 4096 + offa);
            acc = __builtin_amdgcn_mfma_f32_16x16x32_bf16(ah, bh, acc, 0, 0, 0);
            acc = __builtin_amdgcn_mfma_f32_16x16x32_bf16(ah, bl, acc, 0, 0, 0);
            acc = __builtin_amdgcn_mfma_f32_16x16x32_bf16(al, bh, acc, 0, 0, 0);
        }
        __syncthreads();                          // stage complete (vmcnt drained) + reads done
        cur ^= 1;
    }
    int mm = m0 + wc * 16 + (lane & 15);
    int lbase = l0 + wr * 16 + (lane >> 4) * 4;
    #pragma unroll
    for (int i = 0; i < 4; ++i)
        scores[(size_t)(b * SEQ + lbase + i) * SEQ + mm] = acc[i];
}

// transpose 64x64 tile of nr/ni -> K-major bf16 hi/lo
__device__ __forceinline__ void transpose_unit(int m0, int d0, int b, char* smem, int dual,
    const float* __restrict__ nr, const float* __restrict__ ni,
    bf16* __restrict__ nrTh, bf16* __restrict__ nrTl,
    bf16* __restrict__ niTh, bf16* __restrict__ niTl)
{
    float* tr = (float*)smem;           // [64][65]
    float* ti = tr + 64 * 65;
    int c = threadIdx.x & 63, rr = threadIdx.x >> 6;
    #pragma unroll
    for (int i = 0; i < 16; ++i) {
        int r = i * 4 + rr;
        tr[r * 65 + c] = nr[(b * SEQ + m0 + r) * DDIM + d0 + c];
        if (dual) ti[r * 65 + c] = ni[(b * SEQ + m0 + r) * DDIM + d0 + c];
    }
    __syncthreads();
    #pragma unroll
    for (int i = 0; i < 16; ++i) {
        int dd = i * 4 + rr;
        long o = (long)(b * DDIM + d0 + dd) * SEQ + m0 + c;
        float vr = tr[c * 65 + dd];
        bf16 h;
        h = __float2bfloat16(vr); nrTh[o] = h; nrTl[o] = __float2bfloat16(vr - bf2f(h));
        if (dual) {
            float vi = ti[c * 65 + dd];
            h = __float2bfloat16(vi); niTh[o] = h; niTl[o] = __float2bfloat16(vi - bf2f(h));
        }
    }
}

// partial column sums of C (and S when dual) - 16 rows per unit
__device__ __forceinline__ void sums_unit(int c, int b, int dual,
    const float* __restrict__ C, const float* __restrict__ S,
    float* __restrict__ Cp, float* __restrict__ Sp)
{
    int d = threadIdx.x;
    float cs = 0.f, ss = 0.f;
    int base = (b * SEQ + c * 16) * DDIM + d;
    #pragma unroll
    for (int m = 0; m < 16; ++m) {
        cs += C[base + m * DDIM];
        if (dual) ss += S[base + m * DDIM];
    }
    Cp[(b * 24 + c) * DDIM + d] = cs;
    if (dual) Sp[(b * 24 + c) * DDIM + d] = ss;
}

// ---------------- Phase A: scores (288) | transpose (48) | sums (48) in one launch ----------------
__global__ __launch_bounds__(256)
void phaseA_k(const bf16* __restrict__ ASh, const bf16* __restrict__ ASl,
              const bf16* __restrict__ BSh, const bf16* __restrict__ BSl,
              float* __restrict__ attn,
              const float* __restrict__ nr, const float* __restrict__ ni,
              bf16* __restrict__ nrTh, bf16* __restrict__ nrTl,
              bf16* __restrict__ niTh, bf16* __restrict__ niTl,
              const float* __restrict__ Cc, const float* __restrict__ Ss,
              float* __restrict__ Cp, float* __restrict__ Sp, int dual, int kd)
{
    __shared__ __align__(16) char smem[33280];
    int u = blockIdx.x;
    if (u < 288) {
        scores_unit((u % 12) * 32, ((u / 12) % 12) * 32, u / 144, smem, kd,
                    ASh, ASl, BSh, BSl, attn);
    } else if (u < 336) {
        int v = u - 288;
        transpose_unit((v % 6) * 64, ((v / 6) % 4) * 64, v / 24, smem, dual,
                       nr, ni, nrTh, nrTl, niTh, niTl);
    } else {
        int w = u - 336;
        sums_unit(w % 24, w / 24, dual, Cc, Ss, Cp, Sp);
    }
}

// ---------------- Fused softmax + PV GEMM (dual passes merged, B double-buffered) ----------------
// Block: 32 l-rows x 32 d-cols. Softmax from f32 scores wave-parallel, P hi/lo XOR-swizzled
// in LDS, then bf16x3 MFMA vs nrT (and niT when dual) in ONE K-loop. K=384.
__global__ __launch_bounds__(256)
void outfused_k(const float* __restrict__ scores, const int* __restrict__ x,
                const bf16* __restrict__ nrTh, const bf16* __restrict__ nrTl,
                const bf16* __restrict__ niTh, const bf16* __restrict__ niTl,
                float* __restrict__ outr, float* __restrict__ outi, int dual)
{
    __shared__ __align__(16) char PhL[32 * 768];   // P hi, row stride 768B (384 bf16)
    __shared__ __align__(16) char PlL[32 * 768];   // P lo
    __shared__ __align__(16) char Bb[2][16384];    // 2 bufs: nr-hi/nr-lo/ni-hi/ni-lo (4KB each)
    int l0 = blockIdx.x * 32, d0 = blockIdx.y * 32, b = blockIdx.z;
    int tid = threadIdx.x, lane = tid & 63, wid = tid >> 6;

    // mask bits for this lane's 6 columns (col = lane + j*64)
    int msk = 0;
    #pragma unroll
    for (int j = 0; j < 6; ++j)
        if (x[b * SEQ + lane + j * 64] == 0) msk |= (1 << j);

    // softmax: wave w handles rows w*8 .. w*8+7
    #pragma unroll
    for (int r8 = 0; r8 < 8; ++r8) {
        int r = wid * 8 + r8;
        const float* srow = scores + (size_t)(b * SEQ + l0 + r) * SEQ;
        float v[6];
        float mx = -__builtin_inff();
        #pragma unroll
        for (int j = 0; j < 6; ++j) {
            float s = srow[lane + j * 64];
            if (msk & (1 << j)) s = -__builtin_inff();
            v[j] = s;
            mx = fmaxf(mx, s);
        }
        #pragma unroll
        for (int o = 32; o > 0; o >>= 1) mx = fmaxf(mx, __shfl_xor(mx, o, 64));
        float e[6], sum = 0.f;
        #pragma unroll
        for (int j = 0; j < 6; ++j) { e[j] = expf(v[j] - mx); sum += e[j]; }
        #pragma unroll
        for (int o = 32; o > 0; o >>= 1) sum += __shfl_xor(sum, o, 64);
        #pragma unroll
        for (int j = 0; j < 6; ++j) {
            float p = fminf(fmaxf(e[j] / sum, 1e-6f), 1.0f);
            bf16 h = __float2bfloat16(p);
            bf16 l = __float2bfloat16(p - bf2f(h));
            int c2 = (lane + j * 64) * 2;
            int swz = ((c2 & ~15) ^ ((r & 7) << 4)) | (c2 & 15);
            *(bf16*)(PhL + r * 768 + swz) = h;
            *(bf16*)(PlL + r * 768 + swz) = l;
        }
    }

    int wr = wid >> 1, wc = wid & 1;
    int lrow = lane >> 3, cbs = (lane & 7) ^ lrow;
    int half = wid >> 1, hl = wid & 1;             // staging role: rows half*16.., hi/lo = hl
    const bf16* sNr = (hl ? nrTl : nrTh) + (size_t)(b * DDIM + d0) * SEQ;
    const bf16* sNi = (hl ? niTl : niTh) + (size_t)(b * DDIM + d0) * SEQ;

    f32x4 accr = {}, acci = {};

    // stage chunk 0 into buf 0 (barrier below also covers the P-LDS writes)
    {
        bf16* dr = (bf16*)(Bb[0] + hl * 4096 + half * 2048);
        #pragma unroll
        for (int q = 0; q < 2; ++q)
            gload_lds16(sNr + (size_t)(half * 16 + q * 8 + lrow) * SEQ + cbs * 8, dr + q * 512);
        if (dual) {
            bf16* di_ = (bf16*)(Bb[0] + 8192 + hl * 4096 + half * 2048);
            #pragma unroll
            for (int q = 0; q < 2; ++q)
                gload_lds16(sNi + (size_t)(half * 16 + q * 8 + lrow) * SEQ + cbs * 8, di_ + q * 512);
        }
    }
    __syncthreads();
    int cur = 0;
    for (int k0 = 0; k0 < SEQ; k0 += 64) {
        if (k0 + 64 < SEQ) {
            bf16* dr = (bf16*)(Bb[cur ^ 1] + hl * 4096 + half * 2048);
            #pragma unroll
            for (int q = 0; q < 2; ++q)
                gload_lds16(sNr + (size_t)(half * 16 + q * 8 + lrow) * SEQ + (k0 + 64) + cbs * 8,
                            dr + q * 512);
            if (dual) {
                bf16* di_ = (bf16*)(Bb[cur ^ 1] + 8192 + hl * 4096 + half * 2048);
                #pragma unroll
                for (int q = 0; q < 2; ++q)
                    gload_lds16(sNi + (size_t)(half * 16 + q * 8 + lrow) * SEQ + (k0 + 64) + cbs * 8,
                                di_ + q * 512);
            }
        }
        #pragma unroll
        for (int ks = 0; ks < 2; ++ks) {
            int cbk = ks * 64 + (lane >> 4) * 16;         // bytes within 128B k-tile
            int rowb = wc * 16 + (lane & 15);
            int offb = rowb * 128 + (cbk ^ ((rowb & 7) << 4));
            bf16x8 bh = *(const bf16x8*)(Bb[cur] + offb);
            bf16x8 bl = *(const bf16x8*)(Bb[cur] + 4096 + offb);
            int rowa = wr * 16 + (lane & 15);
            int cba = k0 * 2 + cbk;                        // absolute bytes in 768B row
            int offa = rowa * 768 + (cba ^ ((rowa & 7) << 4));
            bf16x8 ah = *(const bf16x8*)(PhL + offa);
            bf16x8 al = *(const bf16x8*)(PlL + offa);
            accr = __builtin_amdgcn_mfma_f32_16x16x32_bf16(ah, bh, accr, 0, 0, 0);
            accr = __builtin_amdgcn_mfma_f32_16x16x32_bf16(ah, bl, accr, 0, 0, 0);
            accr = __builtin_amdgcn_mfma_f32_16x16x32_bf16(al, bh, accr, 0, 0, 0);
            if (dual) {
                bf16x8 bih = *(const bf16x8*)(Bb[cur] + 8192 + offb);
                bf16x8 bil = *(const bf16x8*)(Bb[cur] + 12288 + offb);
                acci = __builtin_amdgcn_mfma_f32_16x16x32_bf16(ah, bih, acci, 0, 0, 0);
                acci = __builtin_amdgcn_mfma_f32_16x16x32_bf16(ah, bil, acci, 0, 0, 0);
                acci = __builtin_amdgcn_mfma_f32_16x16x32_bf16(al, bih, acci, 0, 0, 0);
            }
        }
        __syncthreads();
        cur ^= 1;
    }

    int d = d0 + wc * 16 + (lane & 15);
    int lb = l0 + wr * 16 + (lane >> 4) * 4;
    #pragma unroll
    for (int i = 0; i < 4; ++i) {
        size_t idx = (size_t)(b * SEQ + lb + i) * DDIM + d;
        outr[idx] = accr[i];
        if (dual) outi[idx] = acci[i];
    }
}

// coherence + phase preservation + residual LN update (+ fused next-layer emit)
// Layers >=1: input C==S, Ss/Sp unused -> dotv = 2*C*cs (bitwise == C*cs + S*ss).
// mode 0 emits K=256 folded operands (A = 2*C*wm) for the next layer's scores.
__global__ __launch_bounds__(256)
void update_k(float* __restrict__ realA,
              const float* __restrict__ outr, const float* __restrict__ outi,
              const float* __restrict__ C, const float* __restrict__ S,
              const float* __restrict__ Cp, const float* __restrict__ Sp,
              const void* __restrict__ pp, const void* __restrict__ cfac,
              const void* __restrict__ energy, int layer, int mode,
              const float* __restrict__ wmNext,
              float* __restrict__ nrO, float* __restrict__ Co,
              bf16* __restrict__ ASh, bf16* __restrict__ ASl,
              bf16* __restrict__ BSh, bf16* __restrict__ BSl,
              bf16* __restrict__ Ah, bf16* __restrict__ Al)
{
    __shared__ float red[4];
    bool bf = probe_bf(energy);
    int dualin = (layer == 0);
    int t = blockIdx.x, d = threadIdx.x;
    int b = t / SEQ;
    long idx = (long)t * DDIM + d;
    float cs = 0.f, ss = 0.f;
    #pragma unroll
    for (int c = 0; c < 24; ++c) {
        cs += Cp[(b * 24 + c) * DDIM + d];
        if (dualin) ss += Sp[(b * 24 + c) * DDIM + d];
    }
    float dotv = dualin ? (C[idx] * cs + S[idx] * ss) : 2.f * C[idx] * cs;
    float coh = blk_sum256s(dotv, red) * (1.0f / (384.f * 256.f));
    float cf = (1.f / (1.f + expf(-ldin(cfac, layer, bf)))) * coh;
    float orr = outr[idx], oii = outi[idx];
    float phase = atan2f(oii + 1e-8f, orr + 1e-8f);
    float pres = (1.f / (1.f + expf(-ldin(pp, layer * DDIM + d, bf)))) * cf;
    float pr = orr * cosf(phase * pres);
    float v = realA[idx] + 0.01f * pr;
    float mu = blk_sum256s(v, red) * (1.f / 256.f);
    float dv = v - mu;
    float var = blk_sum256s(dv * dv, red) * (1.f / 256.f);
    float nv = dv / sqrtf(var + 1e-8f);
    nv = fminf(fmaxf(nv, -1.f), 1.f);
    realA[idx] = nv;
    float mu2 = blk_sum256s(nv, red) * (1.f / 256.f);
    float dv2 = nv - mu2;
    float var2 = blk_sum256s(dv2 * dv2, red) * (1.f / 256.f);
    float nn = dv2 / sqrtf(var2 + 1e-5f);
    if (mode == 0) {
        // single-mode emit: C == S (cos==sin of pi/4-type angle); K=256 folded layout
        float ph = atan2f(nn + 1e-8f, nn + 1e-8f);
        float Cv = cosf(ph);
        nrO[idx] = nn;
        Co[idx] = Cv;
        float aC = 2.f * Cv * wmNext[d];         // x2 fold: Sigma_512 == 2*Sigma_256
        long o0 = (long)t * 256 + d;
        bf16 h;
        h = __float2bfloat16(aC); ASh[o0] = h; ASl[o0] = __float2bfloat16(aC - bf2f(h));
        h = __float2bfloat16(Cv); BSh[o0] = h; BSl[o0] = __float2bfloat16(Cv - bf2f(h));
    } else {
        bf16 h = __float2bfloat16(nn);
        Ah[idx] = h;
        Al[idx] = __float2bfloat16(nn - bf2f(h));
    }
}

// ---------------- Stage 1: embedding + phase space + normphase(layer 0) fused ----------------
__global__ __launch_bounds__(256)
void phase_kernel(const int* __restrict__ x, const void* __restrict__ emb,
                  const void* __restrict__ lph, const void* __restrict__ iw,
                  const void* __restrict__ energy, const void* __restrict__ excf,
                  const float* __restrict__ wm0,
                  float* __restrict__ realO,
                  float* __restrict__ nrO, float* __restrict__ niO,
                  float* __restrict__ Co, float* __restrict__ So,
                  bf16* __restrict__ ASh, bf16* __restrict__ ASl,
                  bf16* __restrict__ BSh, bf16* __restrict__ BSl)
{
    __shared__ float red[4];
    bool bf = probe_bf(energy);
    int t = blockIdx.x, d = threadIdx.x;
    int tok = x[t];
    float re = ldin(emb, (long)tok * DDIM + d, bf) * 0.1f;
    float fr = 0.f, fi = 0.f;
    const float ca[3] = {1.0f, -0.5f, -0.5f};
    const float sa[3] = {0.0f, 0.86602540378443864676f, -0.86602540378443864676f};
    #pragma unroll
    for (int i = 0; i < 3; ++i) {
        float pa = tanhf(ldin(lph, i * DDIM + d, bf)) * 3.14159265358979323846f;
        pa = pa * 1.61803398874989484820f;
        float vr = re * cosf(pa);
        float vi = re * sinf(pa);
        float mu = blk_sum256s(vr, red) * (1.f / 256.f);
        float dv = vr - mu;
        float var = blk_sum256s(dv * dv, red) * (1.f / 256.f);
        float r = dv / sqrtf(var + 1e-8f);
        mu = blk_sum256s(vi, red) * (1.f / 256.f);
        float di = vi - mu;
        var = blk_sum256s(di * di, red) * (1.f / 256.f);
        float im = di / sqrtf(var + 1e-8f);
        float w = tanhf(ldin(iw, i * DDIM + d, bf));
        r *= w; im *= w;
        fr = fr + r * ca[i] - im * sa[i];
        fi = fi + r * sa[i] + im * ca[i];
    }
    float amp = sqrtf(fr * fr + fi * fi + 1e-8f);
    float ex = expf(ldin(energy, d, bf)) * ldin(excf, 0, bf);
    if (amp < 0.1f) { fr += ex; fi += ex; }
    float nrm = sqrtf(fr * fr + fi * fi + 1e-8f);
    float rr = fminf(fmaxf(fr / nrm, -1.f), 1.f);
    float ii = fminf(fmaxf(fi / nrm, -1.f), 1.f);
    realO[t * DDIM + d] = rr;
    float mu = blk_sum256s(rr, red) * (1.f / 256.f);
    float dv = rr - mu;
    float var = blk_sum256s(dv * dv, red) * (1.f / 256.f);
    float nrv = dv / sqrtf(var + 1e-5f);
    mu = blk_sum256s(ii, red) * (1.f / 256.f);
    float di = ii - mu;
    var = blk_sum256s(di * di, red) * (1.f / 256.f);
    float niv = di / sqrtf(var + 1e-5f);
    np_emit(t, d, nrv, niv, wm0, nrO, niO, Co, So, ASh, ASl, BSh, BSl);
}

// ---------------- prep1: fold out_w (2000 blocks) | wmean (192 blocks) ----------------
__global__ __launch_bounds__(256)
void prep1_k(const void* __restrict__ W, const void* __restrict__ Wattn,
             const void* __restrict__ energy,
             bf16* __restrict__ Bh, bf16* __restrict__ Bl, float* __restrict__ wmAll)
{
    bool bf = probe_bf(energy);
    int u = blockIdx.x;
    if (u < 2000) {
        __shared__ float tile[64][65];
        int v0 = (u % 500) * 64, d0 = (u / 500) * 64;
        int c = threadIdx.x & 63, rr = threadIdx.x >> 6;
        #pragma unroll
        for (int i = 0; i < 16; ++i) {
            int r = i * 4 + rr;
            long i1 = (long)(d0 + r) * VOC + v0 + c;
            long i2 = (long)(d0 + r + 256) * VOC + v0 + c;
            tile[r][c] = ldin(W, i1, bf) + ldin(W, i2, bf);
        }
        __syncthreads();
        int d = threadIdx.x & 63, vv = threadIdx.x >> 6;
        #pragma unroll
        for (int i = 0; i < 16; ++i) {
            int v = i * 4 + vv;
            float s = tile[d][v];
            bf16 h = __float2bfloat16(s);
            long o = (long)(v0 + v) * DDIM + d0 + d;
            Bh[o] = h;
            Bl[o] = __float2bfloat16(s - __bfloat162float(h));
        }
    } else {
        int row = (u - 2000) * 4 + (threadIdx.x >> 6);
        int lane = threadIdx.x & 63;
        long base = (long)row * DDIM + lane * 4;
        float s = 0.f;
        #pragma unroll
        for (int j = 0; j < 4; ++j) s += ldin(Wattn, base + j, bf);
        #pragma unroll
        for (int o = 32; o > 0; o >>= 1) s += __shfl_down(s, o, 64);
        if (lane == 0) wmAll[row] = s * (1.f / 256.f) * 0.0625f;
    }
}

// ---------------- Final stage: bf16x3 MFMA vocab GEMM ----------------
__global__ __launch_bounds__(512, 4)
void vocab_gemm(const bf16* __restrict__ Ah, const bf16* __restrict__ Al,
                const bf16* __restrict__ Bh, const bf16* __restrict__ Bl,
                const void* __restrict__ bias, const void* __restrict__ energy,
                void* __restrict__ out)
{
    __shared__ bf16 lds[4][128 * 64];
    bool bf = probe_bf(energy);
    int flat = blockIdx.x + blockIdx.y * 6;        // 0..1499
    int xcd = flat & 7, bidx = flat >> 3;
    int swz = (xcd < 4) ? xcd * 188 + bidx : 752 + (xcd - 4) * 187 + bidx;
    int m0 = (swz % 6) * 128, n0 = (swz / 6) * 128;
    int tid = threadIdx.x, lane = tid & 63, wid = tid >> 6;
    int wm = wid >> 2, wn = wid & 3;
    int arr = wid >> 1, half = wid & 1;

    const bf16* src;
    if      (arr == 0) src = Ah + (size_t)m0 * DDIM;
    else if (arr == 1) src = Al + (size_t)m0 * DDIM;
    else if (arr == 2) src = Bh + (size_t)n0 * DDIM;
    else               src = Bl + (size_t)n0 * DDIM;
    src += (size_t)half * 64 * DDIM;
    bf16* ldst = &lds[arr][half * 64 * 64];
    int lrow = lane >> 3;
    int cbs  = (lane & 7) ^ lrow;

    f32x4 acc[4][2] = {};

    for (int k0 = 0; k0 < DDIM; k0 += 64) {
        #pragma unroll
        for (int q = 0; q < 8; ++q) {
            const bf16* gp = src + (size_t)(q * 8 + lrow) * DDIM + k0 + cbs * 8;
            gload_lds16(gp, ldst + q * 512);
        }
        __syncthreads();
        #pragma unroll
        for (int ks = 0; ks < 2; ++ks) {
            int cb = ks * 64 + (lane >> 4) * 16;
            bf16x8 bhf[2], blf[2];
            #pragma unroll
            for (int fn = 0; fn < 2; ++fn) {
                int row = wn * 32 + fn * 16 + (lane & 15);
                int off = row * 128 + (cb ^ ((row & 7) << 4));
                bhf[fn] = *(const bf16x8*)((const char*)&lds[2][0] + off);
                blf[fn] = *(const bf16x8*)((const char*)&lds[3][0] + off);
            }
            #pragma unroll
            for (int fm = 0; fm < 4; ++fm) {
                int row = wm * 64 + fm * 16 + (lane & 15);
                int off = row * 128 + (cb ^ ((row & 7) << 4));
                bf16x8 ah = *(const bf16x8*)((const char*)&lds[0][0] + off);
                bf16x8 al = *(const bf16x8*)((const char*)&lds[1][0] + off);
                #pragma unroll
                for (int fn = 0; fn < 2; ++fn) {
                    acc[fm][fn] = __builtin_amdgcn_mfma_f32_16x16x32_bf16(ah, bhf[fn], acc[fm][fn], 0, 0, 0);
                    acc[fm][fn] = __builtin_amdgcn_mfma_f32_16x16x32_bf16(ah, blf[fn], acc[fm][fn], 0, 0, 0);
                    acc[fm][fn] = __builtin_amdgcn_mfma_f32_16x16x32_bf16(al, bhf[fn], acc[fm][fn], 0, 0, 0);
                }
            }
        }
        __syncthreads();
    }

    #pragma unroll
    for (int fn = 0; fn < 2; ++fn) {
        int n = n0 + wn * 32 + fn * 16 + (lane & 15);
        float bv = ldin(bias, n, bf);
        #pragma unroll
        for (int fm = 0; fm < 4; ++fm) {
            int mbase = m0 + wm * 64 + fm * 16 + (lane >> 4) * 4;
            #pragma unroll
            for (int i = 0; i < 4; ++i) {
                float lg = (acc[fm][fn][i] + bv) * 0.1f;
                lg = fminf(fmaxf(lg, -10.f), 10.f);
                size_t idx = (size_t)(mbase + i) * VOC + n;
                if (bf) ((bf16*)out)[idx] = __float2bfloat16(lg);
                else    ((float*)out)[idx] = lg;
            }
        }
    }
}

extern "C" void kernel_launch(void* const* d_in, const int* in_sizes, int n_in,
                              void* d_out, int out_size, void* d_ws, size_t ws_size,
                              hipStream_t stream) {
    (void)in_sizes; (void)n_in; (void)out_size; (void)ws_size;
    const int*  x        = (const int*)d_in[0];
    const void* emb_real = d_in[1];
    const void* lph      = d_in[3];
    const void* iw       = d_in[4];
    const void* energy   = d_in[5];
    const void* excf     = d_in[6];
    const void* pp       = d_in[7];
    const void* cfac     = d_in[8];
    const void* Wattn    = d_in[9];
    const void* out_w    = d_in[10];
    const void* out_b    = d_in[11];

    float* ws = (float*)d_ws;
    const int TD = NTOK * DDIM;   // 196608
    float* realA = ws;
    float* nr    = realA + TD;
    float* ni    = nr + TD;
    float* Cc    = ni + TD;
    float* Ss    = Cc + TD;
    float* outr  = Ss + TD;
    float* outi  = outr + TD;
    float* attn  = outi + TD;
    float* Cp    = attn + 2 * SEQ * SEQ;
    float* Sp    = Cp + 48 * DDIM;
    float* wmAll = Sp + 48 * DDIM;
    bf16* Ah  = (bf16*)(wmAll + 768);
    bf16* Al  = Ah + (size_t)NTOK * DDIM;
    bf16* Wth = Al + (size_t)NTOK * DDIM;
    bf16* Wtl = Wth + (size_t)VOC * DDIM;
    bf16* ASh = Wtl + (size_t)VOC * DDIM;
    bf16* ASl = ASh + (size_t)NTOK * 512;
    bf16* BSh = ASl + (size_t)NTOK * 512;
    bf16* BSl = BSh + (size_t)NTOK * 512;
    bf16* nrTh = BSl + (size_t)NTOK * 512;     // [2][256][384]
    bf16* nrTl = nrTh + (size_t)NTOK * DDIM;
    bf16* niTh = nrTl + (size_t)NTOK * DDIM;
    bf16* niTl = niTh + (size_t)NTOK * DDIM;

    prep1_k<<<2192, 256, 0, stream>>>(out_w, Wattn, energy, Wth, Wtl, wmAll);
    phase_kernel<<<NTOK, 256, 0, stream>>>(x, emb_real, lph, iw, energy, excf, wmAll,
                                           realA, nr, ni, Cc, Ss, ASh, ASl, BSh, BSl);
    for (int layer = 0; layer < 3; ++layer) {
        int dual = (layer == 0);
        phaseA_k<<<384, 256, 0, stream>>>(ASh, ASl, BSh, BSl, attn, nr, ni,
                                          nrTh, nrTl, niTh, niTl, Cc, Ss, Cp, Sp,
                                          dual, dual ? 512 : 256);
        outfused_k<<<dim3(12, 8, 2), 256, 0, stream>>>(attn, x, nrTh, nrTl, niTh, niTl,
                                                       outr, outi, dual);
        update_k<<<NTOK, 256, 0, stream>>>(realA, outr, dual ? outi : outr, Cc, Ss,
                                           Cp, Sp, pp, cfac, energy, layer,
                                           (layer < 2) ? 0 : 1,
                                           wmAll + (layer + 1 < 3 ? (layer + 1) * DDIM : 0),
                                           nr, Cc, ASh, ASl, BSh, BSl, Ah, Al);
    }
    vocab_gemm<<<dim3(6, VOC / 128), 512, 0, stream>>>(Ah, Al, Wth, Wtl, out_b, energy, (void*)d_out);
}